// Round 1
// baseline (745.569 us; speedup 1.0000x reference)
//
#include <hip/hip_runtime.h>
#include <hip/hip_bf16.h>

#define N_NODES 32768
#define E_EDGES 1048576
#define HID 128
#define G_GRAPHS 128
#define NPG 256
#define NH 8
#define DH 16
#define EPS 1e-5f

// ---------------- helpers ----------------
__device__ __forceinline__ void ln_stats128(float v, float& mean, float& istd, float* red) {
    // 128-thread block (2 waves): mean/invstd over the 128 values (one per thread)
    float s = v, s2 = v * v;
#pragma unroll
    for (int off = 32; off; off >>= 1) { s += __shfl_xor(s, off); s2 += __shfl_xor(s2, off); }
    int w = threadIdx.x >> 6;
    if ((threadIdx.x & 63) == 0) { red[w * 2] = s; red[w * 2 + 1] = s2; }
    __syncthreads();
    float ts = red[0] + red[2], ts2 = red[1] + red[3];
    mean = ts * (1.f / 128.f);
    float var = ts2 * (1.f / 128.f) - mean * mean;
    istd = rsqrtf(var + EPS);
    __syncthreads();
}

// ---------------- CSR build ----------------
__global__ void hist_kernel(const int* __restrict__ dst, int* __restrict__ counts) {
    int e = blockIdx.x * 256 + threadIdx.x;
    if (e < E_EDGES) atomicAdd(&counts[dst[e]], 1);
}

__global__ __launch_bounds__(1024) void scan_kernel(const int* __restrict__ counts,
                                                    int* __restrict__ row_ptr,
                                                    int* __restrict__ fill,
                                                    float* __restrict__ dis) {
    __shared__ int part[1024];
    int t = threadIdx.x;
    int base = t * 32;
    int s = 0;
    for (int i = 0; i < 32; i++) s += counts[base + i];
    part[t] = s;
    __syncthreads();
    for (int off = 1; off < 1024; off <<= 1) {
        int v = (t >= off) ? part[t - off] : 0;
        __syncthreads();
        part[t] += v;
        __syncthreads();
    }
    int run = (t == 0) ? 0 : part[t - 1];
    for (int i = 0; i < 32; i++) {
        int c = counts[base + i];
        row_ptr[base + i] = run;
        fill[base + i] = run;
        dis[base + i] = rsqrtf((float)(c + 1));   // deg includes self-loop
        run += c;
    }
    if (t == 1023) row_ptr[N_NODES] = part[1023];
}

__global__ void scatter_kernel(const int* __restrict__ src, const int* __restrict__ dst,
                               int* __restrict__ fill, int* __restrict__ srcs) {
    int e = blockIdx.x * 256 + threadIdx.x;
    if (e < E_EDGES) {
        int pos = atomicAdd(&fill[dst[e]], 1);
        srcs[pos] = src[e];
    }
}

// ---------------- weight transpose (for @ W.T ops) ----------------
__global__ void transpose4(const float* __restrict__ Wq, const float* __restrict__ Wk,
                           const float* __restrict__ Wv, const float* __restrict__ Wo,
                           float* __restrict__ out) {
    int i = blockIdx.x * 256 + threadIdx.x;   // output idx, 0..16383
    int w = blockIdx.y;
    const float* src = (w == 0) ? Wq : (w == 1) ? Wk : (w == 2) ? Wv : Wo;
    int k = i >> 7, j = i & 127;
    out[w * 16384 + i] = src[j * 128 + k];    // WT[k][j] = W[j][k]
}

// ---------------- input projection + LN + ReLU ----------------
__global__ __launch_bounds__(128) void input_proj(const float* __restrict__ x,
                                                  const float* __restrict__ W,
                                                  const float* __restrict__ b,
                                                  const float* __restrict__ g,
                                                  const float* __restrict__ be,
                                                  float* __restrict__ h) {
    int n = blockIdx.x, j = threadIdx.x;
    __shared__ float xs[15];
    __shared__ float red[4];
    if (j < 15) xs[j] = x[n * 15 + j];
    __syncthreads();
    float acc = b[j];
#pragma unroll
    for (int k = 0; k < 15; k++) acc += xs[k] * W[k * 128 + j];
    float m, is;
    ln_stats128(acc, m, is, red);
    float y = (acc - m) * is * g[j] + be[j];
    h[(long)n * 128 + j] = fmaxf(y, 0.f);
}

// ---------------- 128-wide GEMM: out[N][128] = in[N][128] @ W[128][128] ----------------
// MODE 0: plain.  MODE 1: +bias.  MODE 2: +bias +resid, then LN(gamma,beta).
template <int MODE>
__global__ __launch_bounds__(256) void gemm128(const float* __restrict__ in,
                                               const float* __restrict__ W,
                                               const float* __restrict__ bias,
                                               const float* __restrict__ resid,
                                               const float* __restrict__ gamma,
                                               const float* __restrict__ beta,
                                               float* __restrict__ out) {
    __shared__ float Wl[32 * 128];   // 16KB: K-chunk of W
    __shared__ float hl[64 * 32];    // 8KB:  64 rows x K-chunk
    int tid = threadIdx.x;
    int jq = tid & 31;    // output quad: j = jq*4 .. jq*4+3
    int oct = tid >> 5;   // node octet: nodes oct*8 .. oct*8+7
    long base = (long)blockIdx.x * 64;

    float4 acc[8];
#pragma unroll
    for (int i = 0; i < 8; i++) acc[i] = make_float4(0.f, 0.f, 0.f, 0.f);

    for (int kc = 0; kc < 4; kc++) {
        const float4* Wv4 = (const float4*)(W + kc * 32 * 128);
        float4* Wl4 = (float4*)Wl;
        for (int i = tid; i < 1024; i += 256) Wl4[i] = Wv4[i];
        const float* inb = in + base * 128 + kc * 32;
        for (int i = tid; i < 512; i += 256) {
            int n = i >> 3, c4 = i & 7;
            *(float4*)&hl[n * 32 + c4 * 4] = *(const float4*)&inb[n * 128 + c4 * 4];
        }
        __syncthreads();
#pragma unroll
        for (int kk = 0; kk < 32; kk++) {
            float4 w4 = *(float4*)&Wl[kk * 128 + jq * 4];
#pragma unroll
            for (int n8 = 0; n8 < 8; n8++) {
                float hv = hl[(oct * 8 + n8) * 32 + kk];
                acc[n8].x += hv * w4.x;
                acc[n8].y += hv * w4.y;
                acc[n8].z += hv * w4.z;
                acc[n8].w += hv * w4.w;
            }
        }
        __syncthreads();
    }

    int j0 = jq * 4;
#pragma unroll
    for (int n8 = 0; n8 < 8; n8++) {
        long row = (base + oct * 8 + n8) * 128;
        float4 a = acc[n8];
        if (MODE >= 1) {
            float4 b4 = *(const float4*)&bias[j0];
            a.x += b4.x; a.y += b4.y; a.z += b4.z; a.w += b4.w;
        }
        if (MODE == 2) {
            float4 r4 = *(const float4*)&resid[row + j0];
            a.x += r4.x; a.y += r4.y; a.z += r4.z; a.w += r4.w;
            float s = a.x + a.y + a.z + a.w;
            float s2 = a.x * a.x + a.y * a.y + a.z * a.z + a.w * a.w;
#pragma unroll
            for (int off = 16; off; off >>= 1) { s += __shfl_xor(s, off); s2 += __shfl_xor(s2, off); }
            float mean = s * (1.f / 128.f);
            float var = s2 * (1.f / 128.f) - mean * mean;
            float is = rsqrtf(var + EPS);
            float4 g4 = *(const float4*)&gamma[j0];
            float4 be4 = *(const float4*)&beta[j0];
            a.x = (a.x - mean) * is * g4.x + be4.x;
            a.y = (a.y - mean) * is * g4.y + be4.y;
            a.z = (a.z - mean) * is * g4.z + be4.z;
            a.w = (a.w - mean) * is * g4.w + be4.w;
        }
        *(float4*)&out[row + j0] = a;
    }
}

// ---------------- GCN aggregation + bias + LN + ReLU (+resid) ----------------
__global__ __launch_bounds__(128) void gcn_agg(const float* __restrict__ hW,
                                               const int* __restrict__ row_ptr,
                                               const int* __restrict__ srcs,
                                               const float* __restrict__ dis,
                                               const float* __restrict__ bias,
                                               const float* __restrict__ gamma,
                                               const float* __restrict__ beta,
                                               float* __restrict__ h, int with_resid) {
    int n = blockIdx.x, tid = threadIdx.x;
    __shared__ int sl[128];
    __shared__ float cl[128];
    __shared__ float red[4];
    int r0 = row_ptr[n], r1 = row_ptr[n + 1];
    float dn = dis[n];
    float acc = hW[(long)n * 128 + tid] * (dn * dn);   // self-loop
    for (int b = r0; b < r1; b += 128) {
        int cnt = min(128, r1 - b);
        if (tid < cnt) {
            int s = srcs[b + tid];
            sl[tid] = s;
            cl[tid] = dis[s] * dn;
        }
        __syncthreads();
        int i = 0;
        for (; i + 4 <= cnt; i += 4) {
            int s0 = sl[i], s1 = sl[i + 1], s2 = sl[i + 2], s3 = sl[i + 3];
            float a0 = hW[(long)s0 * 128 + tid];
            float a1 = hW[(long)s1 * 128 + tid];
            float a2 = hW[(long)s2 * 128 + tid];
            float a3 = hW[(long)s3 * 128 + tid];
            acc += a0 * cl[i] + a1 * cl[i + 1] + a2 * cl[i + 2] + a3 * cl[i + 3];
        }
        for (; i < cnt; i++) acc += hW[(long)sl[i] * 128 + tid] * cl[i];
        __syncthreads();
    }
    acc += bias[tid];
    float m, is;
    ln_stats128(acc, m, is, red);
    float y = (acc - m) * is * gamma[tid] + beta[tid];
    y = fmaxf(y, 0.f);
    if (with_resid) y += h[(long)n * 128 + tid];
    h[(long)n * 128 + tid] = y;
}

// ---------------- attention: one block per (graph, head) ----------------
__global__ __launch_bounds__(256) void attention(const float* __restrict__ q,
                                                 const float* __restrict__ k,
                                                 const float* __restrict__ v,
                                                 float* __restrict__ o) {
    int g = blockIdx.x, hh = blockIdx.y;
    __shared__ float ks[NPG * DH];
    __shared__ float vs[NPG * DH];
    int tid = threadIdx.x;
    for (int idx = tid; idx < NPG * DH; idx += 256) {
        int r = idx >> 4, d = idx & 15;
        long row = ((long)g * NPG + r) * 128 + hh * 16;
        ks[idx] = k[row + d];
        vs[idx] = v[row + d];
    }
    __syncthreads();
    float qr[16];
    const float* qp = q + ((long)g * NPG + tid) * 128 + hh * 16;
#pragma unroll
    for (int d = 0; d < 16; d++) qr[d] = qp[d] * 0.25f;   // 1/sqrt(16)
    float m = -1e30f, l = 0.f, acc[16];
#pragma unroll
    for (int d = 0; d < 16; d++) acc[d] = 0.f;
    for (int j = 0; j < NPG; j++) {
        float s = 0.f;
#pragma unroll
        for (int d = 0; d < 16; d++) s += qr[d] * ks[j * 16 + d];
        float nm = fmaxf(m, s);
        float corr = __expf(m - nm);
        float p = __expf(s - nm);
        l = l * corr + p;
        m = nm;
#pragma unroll
        for (int d = 0; d < 16; d++) acc[d] = acc[d] * corr + p * vs[j * 16 + d];
    }
    float inv = 1.f / l;
    float* op = o + ((long)g * NPG + tid) * 128 + hh * 16;
#pragma unroll
    for (int d = 0; d < 16; d++) op[d] = acc[d] * inv;
}

// ---------------- pooling: mean/max/sum per graph ----------------
__global__ __launch_bounds__(128) void pool_kernel(const float* __restrict__ hg,
                                                   float* __restrict__ pooled) {
    int g = blockIdx.x, j = threadIdx.x;
    float s = 0.f, mx = -1e30f;
    for (int i = 0; i < NPG; i++) {
        float vv = hg[((long)g * NPG + i) * 128 + j];
        s += vv;
        mx = fmaxf(mx, vv);
    }
    pooled[g * 384 + j] = s * (1.f / 256.f);
    pooled[g * 384 + 128 + j] = mx;
    pooled[g * 384 + 256 + j] = s;
}

// ---------------- classifier ----------------
__global__ __launch_bounds__(128) void classifier(const float* __restrict__ pooled,
                                                  const float* __restrict__ W1, const float* __restrict__ b1,
                                                  const float* __restrict__ g1, const float* __restrict__ be1,
                                                  const float* __restrict__ W2, const float* __restrict__ b2,
                                                  const float* __restrict__ W3, const float* __restrict__ b3,
                                                  float* __restrict__ out) {
    int g = blockIdx.x, j = threadIdx.x;
    __shared__ float pl[384];
    __shared__ float z1s[128];
    __shared__ float z2s[64];
    __shared__ float red[4];
    for (int i = j; i < 384; i += 128) pl[i] = pooled[g * 384 + i];
    __syncthreads();
    float acc = b1[j];
    for (int kk = 0; kk < 384; kk++) acc += pl[kk] * W1[kk * 128 + j];
    float m, is;
    ln_stats128(acc, m, is, red);
    float y = fmaxf((acc - m) * is * g1[j] + be1[j], 0.f);
    z1s[j] = y;
    __syncthreads();
    if (j < 64) {
        float a2 = b2[j];
        for (int kk = 0; kk < 128; kk++) a2 += z1s[kk] * W2[kk * 64 + j];
        z2s[j] = fmaxf(a2, 0.f);
    }
    __syncthreads();
    if (j < 64) {
        float vv = z2s[j];
        float p0 = vv * W3[j * 2];
        float p1 = vv * W3[j * 2 + 1];
#pragma unroll
        for (int off = 32; off; off >>= 1) { p0 += __shfl_xor(p0, off); p1 += __shfl_xor(p1, off); }
        if (j == 0) {
            out[g * 2] = p0 + b3[0];
            out[g * 2 + 1] = p1 + b3[1];
        }
    }
}

// ---------------- launch ----------------
extern "C" void kernel_launch(void* const* d_in, const int* in_sizes, int n_in,
                              void* d_out, int out_size, void* d_ws, size_t ws_size,
                              hipStream_t stream) {
    const float* x = (const float*)d_in[0];
    const int* ei = (const int*)d_in[1];       // [2, E]: src then dst
    const float* W_in = (const float*)d_in[3];
    const float* b_in = (const float*)d_in[4];
    const float* g_in = (const float*)d_in[5];
    const float* be_in = (const float*)d_in[6];
    const float* Wc = (const float*)d_in[7];   // [3,128,128]
    const float* bc = (const float*)d_in[8];
    const float* gn = (const float*)d_in[9];
    const float* bn = (const float*)d_in[10];
    const float* Wq = (const float*)d_in[11];
    const float* bq = (const float*)d_in[12];
    const float* Wk = (const float*)d_in[13];
    const float* bk = (const float*)d_in[14];
    const float* Wv = (const float*)d_in[15];
    const float* bv = (const float*)d_in[16];
    const float* Wo = (const float*)d_in[17];
    const float* bo = (const float*)d_in[18];
    const float* ga = (const float*)d_in[19];
    const float* ba = (const float*)d_in[20];
    const float* W1 = (const float*)d_in[21];
    const float* b1 = (const float*)d_in[22];
    const float* g1 = (const float*)d_in[23];
    const float* be1 = (const float*)d_in[24];
    const float* W2 = (const float*)d_in[25];
    const float* b2 = (const float*)d_in[26];
    const float* W3 = (const float*)d_in[27];
    const float* b3 = (const float*)d_in[28];
    float* out = (float*)d_out;

    // workspace layout (floats); total ~89MB
    const long NF = (long)N_NODES * 128;
    float* ws = (float*)d_ws;
    float* h = ws;                 // [N,128]
    float* tmp = ws + NF;          // hW scratch / attention output o
    float* qb = ws + 2 * NF;       // q; reused as hg2 after attention
    float* kb = ws + 3 * NF;
    float* vb = ws + 4 * NF;
    float* dis = ws + 5 * NF;      // [N]
    float* pooled = dis + N_NODES;           // [G,384]
    float* wT = pooled + G_GRAPHS * 384;     // 4 x 16384: WqT,WkT,WvT,WoT
    int* ib = (int*)(wT + 4 * 16384);
    int* counts = ib;                        // [N]
    int* row_ptr = ib + N_NODES;             // [N+1]
    int* fill = ib + 2 * N_NODES + 1;        // [N]
    int* srcs = ib + 3 * N_NODES + 1;        // [E]
    float* hg2 = qb;

    const int* e_src = ei;
    const int* e_dst = ei + E_EDGES;

    hipMemsetAsync(counts, 0, N_NODES * sizeof(int), stream);
    transpose4<<<dim3(64, 4), 256, 0, stream>>>(Wq, Wk, Wv, Wo, wT);
    hist_kernel<<<E_EDGES / 256, 256, 0, stream>>>(e_dst, counts);
    scan_kernel<<<1, 1024, 0, stream>>>(counts, row_ptr, fill, dis);
    scatter_kernel<<<E_EDGES / 256, 256, 0, stream>>>(e_src, e_dst, fill, srcs);

    input_proj<<<N_NODES, 128, 0, stream>>>(x, W_in, b_in, g_in, be_in, h);

    for (int i = 0; i < 3; i++) {
        gemm128<0><<<N_NODES / 64, 256, 0, stream>>>(h, Wc + i * 16384, nullptr, nullptr,
                                                     nullptr, nullptr, tmp);
        gcn_agg<<<N_NODES, 128, 0, stream>>>(tmp, row_ptr, srcs, dis, bc + i * 128,
                                             gn + i * 128, bn + i * 128, h, i > 0);
    }

    gemm128<1><<<N_NODES / 64, 256, 0, stream>>>(h, wT + 0 * 16384, bq, nullptr, nullptr, nullptr, qb);
    gemm128<1><<<N_NODES / 64, 256, 0, stream>>>(h, wT + 1 * 16384, bk, nullptr, nullptr, nullptr, kb);
    gemm128<1><<<N_NODES / 64, 256, 0, stream>>>(h, wT + 2 * 16384, bv, nullptr, nullptr, nullptr, vb);

    attention<<<dim3(G_GRAPHS, NH), 256, 0, stream>>>(qb, kb, vb, tmp);

    gemm128<2><<<N_NODES / 64, 256, 0, stream>>>(tmp, wT + 3 * 16384, bo, h, ga, ba, hg2);

    pool_kernel<<<G_GRAPHS, 128, 0, stream>>>(hg2, pooled);
    classifier<<<G_GRAPHS, 128, 0, stream>>>(pooled, W1, b1, g1, be1, W2, b2, W3, b3, out);
}

// Round 2
// 701.539 us; speedup vs baseline: 1.0628x; 1.0628x over previous
//
#include <hip/hip_runtime.h>
#include <hip/hip_bf16.h>

#define N_NODES 32768
#define E_EDGES 1048576
#define HID 128
#define G_GRAPHS 128
#define NPG 256
#define NH 8
#define DH 16
#define EPS 1e-5f

// ---------------- helpers ----------------
__device__ __forceinline__ void ln_stats128(float v, float& mean, float& istd, float* red) {
    float s = v, s2 = v * v;
#pragma unroll
    for (int off = 32; off; off >>= 1) { s += __shfl_xor(s, off); s2 += __shfl_xor(s2, off); }
    int w = threadIdx.x >> 6;
    if ((threadIdx.x & 63) == 0) { red[w * 2] = s; red[w * 2 + 1] = s2; }
    __syncthreads();
    float ts = red[0] + red[2], ts2 = red[1] + red[3];
    mean = ts * (1.f / 128.f);
    float var = ts2 * (1.f / 128.f) - mean * mean;
    istd = rsqrtf(var + EPS);
    __syncthreads();
}

// ---------------- CSR build ----------------
__global__ void hist_kernel(const int* __restrict__ dst, int* __restrict__ counts) {
    int e = blockIdx.x * 256 + threadIdx.x;
    if (e < E_EDGES) atomicAdd(&counts[dst[e]], 1);
}

__global__ __launch_bounds__(1024) void scan_kernel(const int* __restrict__ counts,
                                                    int* __restrict__ row_ptr,
                                                    int* __restrict__ fill,
                                                    float* __restrict__ dis) {
    __shared__ int part[1024];
    int t = threadIdx.x;
    int4 c[8];
    const int4* c4 = (const int4*)(counts + t * 32);
    int s = 0;
#pragma unroll
    for (int i = 0; i < 8; i++) { c[i] = c4[i]; s += c[i].x + c[i].y + c[i].z + c[i].w; }
    part[t] = s;
    __syncthreads();
    for (int off = 1; off < 1024; off <<= 1) {
        int v = (t >= off) ? part[t - off] : 0;
        __syncthreads();
        part[t] += v;
        __syncthreads();
    }
    int run = (t == 0) ? 0 : part[t - 1];
    int base = t * 32;
#pragma unroll
    for (int i = 0; i < 8; i++) {
        int4 cc = c[i];
        int p0 = run; run += cc.x;
        int p1 = run; run += cc.y;
        int p2 = run; run += cc.z;
        int p3 = run; run += cc.w;
        int4 rp = make_int4(p0, p1, p2, p3);
        *(int4*)&row_ptr[base + i * 4] = rp;
        *(int4*)&fill[base + i * 4] = rp;
        float4 dd = make_float4(rsqrtf((float)(cc.x + 1)), rsqrtf((float)(cc.y + 1)),
                                rsqrtf((float)(cc.z + 1)), rsqrtf((float)(cc.w + 1)));
        *(float4*)&dis[base + i * 4] = dd;
    }
    if (t == 1023) row_ptr[N_NODES] = run;
}

__global__ void scatter_kernel(const int* __restrict__ src, const int* __restrict__ dst,
                               int* __restrict__ fill, int* __restrict__ srcs) {
    int e = blockIdx.x * 256 + threadIdx.x;
    if (e < E_EDGES) {
        int pos = atomicAdd(&fill[dst[e]], 1);
        srcs[pos] = src[e];
    }
}

// ---------------- weight transpose + bias staging ----------------
__global__ void transpose4(const float* __restrict__ Wq, const float* __restrict__ Wk,
                           const float* __restrict__ Wv, const float* __restrict__ Wo,
                           const float* __restrict__ bq, const float* __restrict__ bk,
                           const float* __restrict__ bv,
                           float* __restrict__ out, float* __restrict__ bT) {
    int i = blockIdx.x * 256 + threadIdx.x;   // 0..16383
    int w = blockIdx.y;
    const float* src = (w == 0) ? Wq : (w == 1) ? Wk : (w == 2) ? Wv : Wo;
    int k = i >> 7, j = i & 127;
    out[w * 16384 + i] = src[j * 128 + k];    // WT[k][j] = W[j][k]
    if (w < 3 && i < 128) {
        const float* bs = (w == 0) ? bq : (w == 1) ? bk : bv;
        bT[w * 128 + i] = bs[i];
    }
}

// ---------------- input projection + LN + ReLU ----------------
__global__ __launch_bounds__(128) void input_proj(const float* __restrict__ x,
                                                  const float* __restrict__ W,
                                                  const float* __restrict__ b,
                                                  const float* __restrict__ g,
                                                  const float* __restrict__ be,
                                                  float* __restrict__ h) {
    int n = blockIdx.x, j = threadIdx.x;
    __shared__ float xs[15];
    __shared__ float red[4];
    if (j < 15) xs[j] = x[n * 15 + j];
    __syncthreads();
    float acc = b[j];
#pragma unroll
    for (int k = 0; k < 15; k++) acc += xs[k] * W[k * 128 + j];
    float m, is;
    ln_stats128(acc, m, is, red);
    float y = (acc - m) * is * g[j] + be[j];
    h[(long)n * 128 + j] = fmaxf(y, 0.f);
}

// ---------------- 128-wide GEMM body ----------------
// MODE 0: plain.  MODE 1: +bias.  MODE 2: +bias +resid, then LN(gamma,beta).
template <int MODE>
__device__ __forceinline__ void gemm_body(const float* __restrict__ in,
                                          const float* __restrict__ W,
                                          const float* __restrict__ bias,
                                          const float* __restrict__ resid,
                                          const float* __restrict__ gamma,
                                          const float* __restrict__ beta,
                                          float* __restrict__ out) {
    __shared__ float Wl[32 * 128];
    __shared__ float hl[64 * 32];
    int tid = threadIdx.x;
    int jq = tid & 31;
    int oct = tid >> 5;
    long base = (long)blockIdx.x * 64;

    float4 acc[8];
#pragma unroll
    for (int i = 0; i < 8; i++) acc[i] = make_float4(0.f, 0.f, 0.f, 0.f);

    for (int kc = 0; kc < 4; kc++) {
        const float4* Wv4 = (const float4*)(W + kc * 32 * 128);
        float4* Wl4 = (float4*)Wl;
        for (int i = tid; i < 1024; i += 256) Wl4[i] = Wv4[i];
        const float* inb = in + base * 128 + kc * 32;
        for (int i = tid; i < 512; i += 256) {
            int n = i >> 3, c4 = i & 7;
            *(float4*)&hl[n * 32 + c4 * 4] = *(const float4*)&inb[n * 128 + c4 * 4];
        }
        __syncthreads();
#pragma unroll
        for (int kk = 0; kk < 32; kk++) {
            float4 w4 = *(float4*)&Wl[kk * 128 + jq * 4];
#pragma unroll
            for (int n8 = 0; n8 < 8; n8++) {
                float hv = hl[(oct * 8 + n8) * 32 + kk];
                acc[n8].x += hv * w4.x;
                acc[n8].y += hv * w4.y;
                acc[n8].z += hv * w4.z;
                acc[n8].w += hv * w4.w;
            }
        }
        __syncthreads();
    }

    int j0 = jq * 4;
#pragma unroll
    for (int n8 = 0; n8 < 8; n8++) {
        long row = (base + oct * 8 + n8) * 128;
        float4 a = acc[n8];
        if (MODE >= 1) {
            float4 b4 = *(const float4*)&bias[j0];
            a.x += b4.x; a.y += b4.y; a.z += b4.z; a.w += b4.w;
        }
        if (MODE == 2) {
            float4 r4 = *(const float4*)&resid[row + j0];
            a.x += r4.x; a.y += r4.y; a.z += r4.z; a.w += r4.w;
            float s = a.x + a.y + a.z + a.w;
            float s2 = a.x * a.x + a.y * a.y + a.z * a.z + a.w * a.w;
#pragma unroll
            for (int off = 16; off; off >>= 1) { s += __shfl_xor(s, off); s2 += __shfl_xor(s2, off); }
            float mean = s * (1.f / 128.f);
            float var = s2 * (1.f / 128.f) - mean * mean;
            float is = rsqrtf(var + EPS);
            float4 g4 = *(const float4*)&gamma[j0];
            float4 be4 = *(const float4*)&beta[j0];
            a.x = (a.x - mean) * is * g4.x + be4.x;
            a.y = (a.y - mean) * is * g4.y + be4.y;
            a.z = (a.z - mean) * is * g4.z + be4.z;
            a.w = (a.w - mean) * is * g4.w + be4.w;
        }
        *(float4*)&out[row + j0] = a;
    }
}

template <int MODE>
__global__ __launch_bounds__(256) void gemm128(const float* __restrict__ in,
                                               const float* __restrict__ W,
                                               const float* __restrict__ bias,
                                               const float* __restrict__ resid,
                                               const float* __restrict__ gamma,
                                               const float* __restrict__ beta,
                                               float* __restrict__ out) {
    gemm_body<MODE>(in, W, bias, resid, gamma, beta, out);
}

__global__ __launch_bounds__(256) void gemm_qkv(const float* __restrict__ in,
                                                const float* __restrict__ wT,
                                                const float* __restrict__ bT,
                                                float* __restrict__ outb) {
    int y = blockIdx.y;
    gemm_body<1>(in, wT + y * 16384, bT + y * 128, nullptr, nullptr, nullptr,
                 outb + (long)y * N_NODES * 128);
}

// ---------------- GCN aggregation + bias + LN + ReLU (+resid) ----------------
__global__ __launch_bounds__(128) void gcn_agg(const float* __restrict__ hW,
                                               const int* __restrict__ row_ptr,
                                               const int* __restrict__ srcs,
                                               const float* __restrict__ dis,
                                               const float* __restrict__ bias,
                                               const float* __restrict__ gamma,
                                               const float* __restrict__ beta,
                                               float* __restrict__ h, int with_resid) {
    int n = blockIdx.x, tid = threadIdx.x;
    __shared__ int sl[128];
    __shared__ float cl[128];
    __shared__ float red[4];
    int r0 = row_ptr[n], r1 = row_ptr[n + 1];
    float dn = dis[n];
    float acc = hW[(long)n * 128 + tid] * (dn * dn);   // self-loop
    for (int b = r0; b < r1; b += 128) {
        int cnt = min(128, r1 - b);
        if (tid < cnt) {
            int s = srcs[b + tid];
            sl[tid] = s;
            cl[tid] = dis[s] * dn;
        }
        __syncthreads();
        int i = 0;
        for (; i + 4 <= cnt; i += 4) {
            int s0 = sl[i], s1 = sl[i + 1], s2 = sl[i + 2], s3 = sl[i + 3];
            float a0 = hW[(long)s0 * 128 + tid];
            float a1 = hW[(long)s1 * 128 + tid];
            float a2 = hW[(long)s2 * 128 + tid];
            float a3 = hW[(long)s3 * 128 + tid];
            acc += a0 * cl[i] + a1 * cl[i + 1] + a2 * cl[i + 2] + a3 * cl[i + 3];
        }
        for (; i < cnt; i++) acc += hW[(long)sl[i] * 128 + tid] * cl[i];
        __syncthreads();
    }
    acc += bias[tid];
    float m, is;
    ln_stats128(acc, m, is, red);
    float y = (acc - m) * is * gamma[tid] + beta[tid];
    y = fmaxf(y, 0.f);
    if (with_resid) y += h[(long)n * 128 + tid];
    h[(long)n * 128 + tid] = y;
}

// ---------------- attention v2: no-max softmax (scores bounded), one thread/query ----------------
__global__ __launch_bounds__(256) void attention(const float* __restrict__ q,
                                                 const float* __restrict__ k,
                                                 const float* __restrict__ v,
                                                 float* __restrict__ o) {
    int g = blockIdx.x, hh = blockIdx.y;
    __shared__ float ks[NPG * DH];
    __shared__ float vs[NPG * DH];
    int tid = threadIdx.x;
    long gbase = (long)g * NPG * 128 + hh * 16;
    for (int idx = tid; idx < NPG * DH; idx += 256) {
        int r = idx >> 4, d = idx & 15;
        ks[idx] = k[gbase + (long)r * 128 + d];
        vs[idx] = v[gbase + (long)r * 128 + d];
    }
    __syncthreads();
    float qr[16];
    const float* qp = q + gbase + (long)tid * 128;
#pragma unroll
    for (int d = 0; d < 16; d++) qr[d] = qp[d] * 0.25f;   // 1/sqrt(16)
    float l = 0.f;
    float acc[16];
#pragma unroll
    for (int d = 0; d < 16; d++) acc[d] = 0.f;
#pragma unroll 2
    for (int j = 0; j < NPG; j++) {
        const float4* k4 = (const float4*)&ks[j * 16];
        float4 ka = k4[0], kb = k4[1], kc = k4[2], kd = k4[3];
        float s = qr[0] * ka.x + qr[1] * ka.y + qr[2] * ka.z + qr[3] * ka.w
                + qr[4] * kb.x + qr[5] * kb.y + qr[6] * kb.z + qr[7] * kb.w
                + qr[8] * kc.x + qr[9] * kc.y + qr[10] * kc.z + qr[11] * kc.w
                + qr[12] * kd.x + qr[13] * kd.y + qr[14] * kd.z + qr[15] * kd.w;
        float p = __expf(s);   // scores bounded (~|s|<10): no max subtraction needed
        l += p;
        const float4* v4 = (const float4*)&vs[j * 16];
        float4 va = v4[0], vb = v4[1], vc = v4[2], vd = v4[3];
        acc[0] += p * va.x;  acc[1] += p * va.y;  acc[2] += p * va.z;  acc[3] += p * va.w;
        acc[4] += p * vb.x;  acc[5] += p * vb.y;  acc[6] += p * vb.z;  acc[7] += p * vb.w;
        acc[8] += p * vc.x;  acc[9] += p * vc.y;  acc[10] += p * vc.z; acc[11] += p * vc.w;
        acc[12] += p * vd.x; acc[13] += p * vd.y; acc[14] += p * vd.z; acc[15] += p * vd.w;
    }
    float inv = 1.f / l;
    float* op = o + gbase + (long)tid * 128;
#pragma unroll
    for (int d = 0; d < 16; d++) op[d] = acc[d] * inv;
}

// ---------------- pooling: mean/max/sum per graph ----------------
__global__ __launch_bounds__(512) void pool_kernel(const float* __restrict__ hg,
                                                   float* __restrict__ pooled) {
    int g = blockIdx.x;
    int tid = threadIdx.x;
    int j = tid & 127, grp = tid >> 7;   // 4 row-groups x 64 rows
    __shared__ float ssum[4][128];
    __shared__ float smax[4][128];
    float s = 0.f, mx = -1e30f;
    for (int i = grp * 64; i < grp * 64 + 64; i++) {
        float vv = hg[((long)g * NPG + i) * 128 + j];
        s += vv;
        mx = fmaxf(mx, vv);
    }
    ssum[grp][j] = s;
    smax[grp][j] = mx;
    __syncthreads();
    if (grp == 0) {
        float ts = ssum[0][j] + ssum[1][j] + ssum[2][j] + ssum[3][j];
        float tm = fmaxf(fmaxf(smax[0][j], smax[1][j]), fmaxf(smax[2][j], smax[3][j]));
        pooled[g * 384 + j] = ts * (1.f / 256.f);
        pooled[g * 384 + 128 + j] = tm;
        pooled[g * 384 + 256 + j] = ts;
    }
}

// ---------------- classifier ----------------
__global__ __launch_bounds__(128) void classifier(const float* __restrict__ pooled,
                                                  const float* __restrict__ W1, const float* __restrict__ b1,
                                                  const float* __restrict__ g1, const float* __restrict__ be1,
                                                  const float* __restrict__ W2, const float* __restrict__ b2,
                                                  const float* __restrict__ W3, const float* __restrict__ b3,
                                                  float* __restrict__ out) {
    int g = blockIdx.x, j = threadIdx.x;
    __shared__ float pl[384];
    __shared__ float z1s[128];
    __shared__ float z2s[64];
    __shared__ float red[4];
    for (int i = j; i < 384; i += 128) pl[i] = pooled[g * 384 + i];
    __syncthreads();
    float acc = b1[j];
    for (int kk = 0; kk < 384; kk++) acc += pl[kk] * W1[kk * 128 + j];
    float m, is;
    ln_stats128(acc, m, is, red);
    float y = fmaxf((acc - m) * is * g1[j] + be1[j], 0.f);
    z1s[j] = y;
    __syncthreads();
    if (j < 64) {
        float a2 = b2[j];
        for (int kk = 0; kk < 128; kk++) a2 += z1s[kk] * W2[kk * 64 + j];
        z2s[j] = fmaxf(a2, 0.f);
    }
    __syncthreads();
    if (j < 64) {
        float vv = z2s[j];
        float p0 = vv * W3[j * 2];
        float p1 = vv * W3[j * 2 + 1];
#pragma unroll
        for (int off = 32; off; off >>= 1) { p0 += __shfl_xor(p0, off); p1 += __shfl_xor(p1, off); }
        if (j == 0) {
            out[g * 2] = p0 + b3[0];
            out[g * 2 + 1] = p1 + b3[1];
        }
    }
}

// ---------------- launch ----------------
extern "C" void kernel_launch(void* const* d_in, const int* in_sizes, int n_in,
                              void* d_out, int out_size, void* d_ws, size_t ws_size,
                              hipStream_t stream) {
    const float* x = (const float*)d_in[0];
    const int* ei = (const int*)d_in[1];       // [2, E]: src then dst
    const float* W_in = (const float*)d_in[3];
    const float* b_in = (const float*)d_in[4];
    const float* g_in = (const float*)d_in[5];
    const float* be_in = (const float*)d_in[6];
    const float* Wc = (const float*)d_in[7];   // [3,128,128]
    const float* bc = (const float*)d_in[8];
    const float* gn = (const float*)d_in[9];
    const float* bn = (const float*)d_in[10];
    const float* Wq = (const float*)d_in[11];
    const float* bq = (const float*)d_in[12];
    const float* Wk = (const float*)d_in[13];
    const float* bk = (const float*)d_in[14];
    const float* Wv = (const float*)d_in[15];
    const float* bv = (const float*)d_in[16];
    const float* Wo = (const float*)d_in[17];
    const float* bo = (const float*)d_in[18];
    const float* ga = (const float*)d_in[19];
    const float* ba = (const float*)d_in[20];
    const float* W1 = (const float*)d_in[21];
    const float* b1 = (const float*)d_in[22];
    const float* g1 = (const float*)d_in[23];
    const float* be1 = (const float*)d_in[24];
    const float* W2 = (const float*)d_in[25];
    const float* b2 = (const float*)d_in[26];
    const float* W3 = (const float*)d_in[27];
    const float* b3 = (const float*)d_in[28];
    float* out = (float*)d_out;

    const long NF = (long)N_NODES * 128;
    float* ws = (float*)d_ws;
    float* h = ws;                 // [N,128]
    float* tmp = ws + NF;          // hW scratch / attention output o
    float* qb = ws + 2 * NF;       // q,k,v contiguous (gemm_qkv); qb reused as hg2
    float* kb = ws + 3 * NF;
    float* vb = ws + 4 * NF;
    float* dis = ws + 5 * NF;      // [N]
    float* pooled = dis + N_NODES;           // [G,384]
    float* wT = pooled + G_GRAPHS * 384;     // 4 x 16384
    float* bT = wT + 4 * 16384;              // 3 x 128 (bq,bk,bv staged)
    int* ib = (int*)(bT + 3 * 128);
    int* counts = ib;                        // [N]
    int* fill = ib + N_NODES;                // [N]
    int* srcs = ib + 2 * N_NODES;            // [E]
    int* row_ptr = srcs + E_EDGES;           // [N+1]
    float* hg2 = qb;

    const int* e_src = ei;
    const int* e_dst = ei + E_EDGES;

    hipMemsetAsync(counts, 0, N_NODES * sizeof(int), stream);
    transpose4<<<dim3(64, 4), 256, 0, stream>>>(Wq, Wk, Wv, Wo, bq, bk, bv, wT, bT);
    hist_kernel<<<E_EDGES / 256, 256, 0, stream>>>(e_dst, counts);
    scan_kernel<<<1, 1024, 0, stream>>>(counts, row_ptr, fill, dis);
    scatter_kernel<<<E_EDGES / 256, 256, 0, stream>>>(e_src, e_dst, fill, srcs);

    input_proj<<<N_NODES, 128, 0, stream>>>(x, W_in, b_in, g_in, be_in, h);

    for (int i = 0; i < 3; i++) {
        gemm128<0><<<N_NODES / 64, 256, 0, stream>>>(h, Wc + i * 16384, nullptr, nullptr,
                                                     nullptr, nullptr, tmp);
        gcn_agg<<<N_NODES, 128, 0, stream>>>(tmp, row_ptr, srcs, dis, bc + i * 128,
                                             gn + i * 128, bn + i * 128, h, i > 0);
    }

    gemm_qkv<<<dim3(N_NODES / 64, 3), 256, 0, stream>>>(h, wT, bT, qb);

    attention<<<dim3(G_GRAPHS, NH), 256, 0, stream>>>(qb, kb, vb, tmp);

    gemm128<2><<<N_NODES / 64, 256, 0, stream>>>(tmp, wT + 3 * 16384, bo, h, ga, ba, hg2);

    pool_kernel<<<G_GRAPHS, 512, 0, stream>>>(hg2, pooled);
    classifier<<<G_GRAPHS, 128, 0, stream>>>(pooled, W1, b1, g1, be1, W2, b2, W3, b3, out);
}

// Round 3
// 597.329 us; speedup vs baseline: 1.2482x; 1.1745x over previous
//
#include <hip/hip_runtime.h>
#include <hip/hip_bf16.h>

#define N_NODES 32768
#define E_EDGES 1048576
#define HID 128
#define G_GRAPHS 128
#define NPG 256
#define NH 8
#define DH 16
#define EPS 1e-5f

typedef __attribute__((ext_vector_type(4))) float f32x4;
typedef __attribute__((ext_vector_type(4))) short bf16x4;

static __device__ __forceinline__ unsigned short bfbits(float f) {
    return __builtin_bit_cast(unsigned short, __float2bfloat16(f));
}
static __device__ __forceinline__ float bf2f(unsigned short u) {
    return __builtin_bit_cast(float, (unsigned)u << 16);
}

// ---------------- helpers ----------------
__device__ __forceinline__ void ln_stats128(float v, float& mean, float& istd, float* red) {
    float s = v, s2 = v * v;
#pragma unroll
    for (int off = 32; off; off >>= 1) { s += __shfl_xor(s, off); s2 += __shfl_xor(s2, off); }
    int w = threadIdx.x >> 6;
    if ((threadIdx.x & 63) == 0) { red[w * 2] = s; red[w * 2 + 1] = s2; }
    __syncthreads();
    float ts = red[0] + red[2], ts2 = red[1] + red[3];
    mean = ts * (1.f / 128.f);
    float var = ts2 * (1.f / 128.f) - mean * mean;
    istd = rsqrtf(var + EPS);
    __syncthreads();
}

// ---------------- CSR build ----------------
__global__ void hist_kernel(const int* __restrict__ dst, int* __restrict__ counts) {
    int e = blockIdx.x * 256 + threadIdx.x;
    if (e < E_EDGES) atomicAdd(&counts[dst[e]], 1);
}

__global__ __launch_bounds__(1024) void scan_kernel(const int* __restrict__ counts,
                                                    int* __restrict__ row_ptr,
                                                    int* __restrict__ fill,
                                                    float* __restrict__ dis) {
    __shared__ int part[1024];
    int t = threadIdx.x;
    int4 c[8];
    const int4* c4 = (const int4*)(counts + t * 32);
    int s = 0;
#pragma unroll
    for (int i = 0; i < 8; i++) { c[i] = c4[i]; s += c[i].x + c[i].y + c[i].z + c[i].w; }
    part[t] = s;
    __syncthreads();
    for (int off = 1; off < 1024; off <<= 1) {
        int v = (t >= off) ? part[t - off] : 0;
        __syncthreads();
        part[t] += v;
        __syncthreads();
    }
    int run = (t == 0) ? 0 : part[t - 1];
    int base = t * 32;
#pragma unroll
    for (int i = 0; i < 8; i++) {
        int4 cc = c[i];
        int p0 = run; run += cc.x;
        int p1 = run; run += cc.y;
        int p2 = run; run += cc.z;
        int p3 = run; run += cc.w;
        int4 rp = make_int4(p0, p1, p2, p3);
        *(int4*)&row_ptr[base + i * 4] = rp;
        *(int4*)&fill[base + i * 4] = rp;
        float4 dd = make_float4(rsqrtf((float)(cc.x + 1)), rsqrtf((float)(cc.y + 1)),
                                rsqrtf((float)(cc.z + 1)), rsqrtf((float)(cc.w + 1)));
        *(float4*)&dis[base + i * 4] = dd;
    }
    if (t == 1023) row_ptr[N_NODES] = run;
}

__global__ void scatter_kernel(const int* __restrict__ src, const int* __restrict__ dst,
                               int* __restrict__ fill, int* __restrict__ srcs) {
    int e = blockIdx.x * 256 + threadIdx.x;
    if (e < E_EDGES) {
        int pos = atomicAdd(&fill[dst[e]], 1);
        srcs[pos] = src[e];
    }
}

// ---------------- weight transpose + bias staging ----------------
__global__ void transpose4(const float* __restrict__ Wq, const float* __restrict__ Wk,
                           const float* __restrict__ Wv, const float* __restrict__ Wo,
                           const float* __restrict__ bq, const float* __restrict__ bk,
                           const float* __restrict__ bv,
                           float* __restrict__ out, float* __restrict__ bT) {
    int i = blockIdx.x * 256 + threadIdx.x;   // 0..16383
    int w = blockIdx.y;
    const float* src = (w == 0) ? Wq : (w == 1) ? Wk : (w == 2) ? Wv : Wo;
    int k = i >> 7, j = i & 127;
    out[w * 16384 + i] = src[j * 128 + k];    // WT[k][j] = W[j][k]
    if (w < 3 && i < 128) {
        const float* bs = (w == 0) ? bq : (w == 1) ? bk : bv;
        bT[w * 128 + i] = bs[i];
    }
}

// ---------------- input projection + LN + ReLU ----------------
__global__ __launch_bounds__(128) void input_proj(const float* __restrict__ x,
                                                  const float* __restrict__ W,
                                                  const float* __restrict__ b,
                                                  const float* __restrict__ g,
                                                  const float* __restrict__ be,
                                                  float* __restrict__ h) {
    int n = blockIdx.x, j = threadIdx.x;
    __shared__ float xs[15];
    __shared__ float red[4];
    if (j < 15) xs[j] = x[n * 15 + j];
    __syncthreads();
    float acc = b[j];
#pragma unroll
    for (int k = 0; k < 15; k++) acc += xs[k] * W[k * 128 + j];
    float m, is;
    ln_stats128(acc, m, is, red);
    float y = (acc - m) * is * g[j] + be[j];
    h[(long)n * 128 + j] = fmaxf(y, 0.f);
}

// ---------------- 128-wide GEMM body ----------------
// MODE 0: plain.  MODE 1: +bias.  MODE 2: +bias +resid, then LN(gamma,beta).
// OUT16: write bf16 (ushort) instead of fp32.
template <int MODE, int OUT16>
__device__ __forceinline__ void gemm_body(const float* __restrict__ in,
                                          const float* __restrict__ W,
                                          const float* __restrict__ bias,
                                          const float* __restrict__ resid,
                                          const float* __restrict__ gamma,
                                          const float* __restrict__ beta,
                                          void* __restrict__ outv) {
    __shared__ float Wl[32 * 128];
    __shared__ float hl[64 * 32];
    int tid = threadIdx.x;
    int jq = tid & 31;
    int oct = tid >> 5;
    long base = (long)blockIdx.x * 64;

    float4 acc[8];
#pragma unroll
    for (int i = 0; i < 8; i++) acc[i] = make_float4(0.f, 0.f, 0.f, 0.f);

    for (int kc = 0; kc < 4; kc++) {
        const float4* Wv4 = (const float4*)(W + kc * 32 * 128);
        float4* Wl4 = (float4*)Wl;
        for (int i = tid; i < 1024; i += 256) Wl4[i] = Wv4[i];
        const float* inb = in + base * 128 + kc * 32;
        for (int i = tid; i < 512; i += 256) {
            int n = i >> 3, c4 = i & 7;
            *(float4*)&hl[n * 32 + c4 * 4] = *(const float4*)&inb[n * 128 + c4 * 4];
        }
        __syncthreads();
#pragma unroll
        for (int kk = 0; kk < 32; kk++) {
            float4 w4 = *(float4*)&Wl[kk * 128 + jq * 4];
#pragma unroll
            for (int n8 = 0; n8 < 8; n8++) {
                float hv = hl[(oct * 8 + n8) * 32 + kk];
                acc[n8].x += hv * w4.x;
                acc[n8].y += hv * w4.y;
                acc[n8].z += hv * w4.z;
                acc[n8].w += hv * w4.w;
            }
        }
        __syncthreads();
    }

    int j0 = jq * 4;
#pragma unroll
    for (int n8 = 0; n8 < 8; n8++) {
        long row = (base + oct * 8 + n8) * 128;
        float4 a = acc[n8];
        if (MODE >= 1) {
            float4 b4 = *(const float4*)&bias[j0];
            a.x += b4.x; a.y += b4.y; a.z += b4.z; a.w += b4.w;
        }
        if (MODE == 2) {
            float4 r4 = *(const float4*)&resid[row + j0];
            a.x += r4.x; a.y += r4.y; a.z += r4.z; a.w += r4.w;
            float s = a.x + a.y + a.z + a.w;
            float s2 = a.x * a.x + a.y * a.y + a.z * a.z + a.w * a.w;
#pragma unroll
            for (int off = 16; off; off >>= 1) { s += __shfl_xor(s, off); s2 += __shfl_xor(s2, off); }
            float mean = s * (1.f / 128.f);
            float var = s2 * (1.f / 128.f) - mean * mean;
            float is = rsqrtf(var + EPS);
            float4 g4 = *(const float4*)&gamma[j0];
            float4 be4 = *(const float4*)&beta[j0];
            a.x = (a.x - mean) * is * g4.x + be4.x;
            a.y = (a.y - mean) * is * g4.y + be4.y;
            a.z = (a.z - mean) * is * g4.z + be4.z;
            a.w = (a.w - mean) * is * g4.w + be4.w;
        }
        if (OUT16) {
            unsigned short* o16 = (unsigned short*)outv;
            ushort4 st;
            st.x = bfbits(a.x); st.y = bfbits(a.y); st.z = bfbits(a.z); st.w = bfbits(a.w);
            *(ushort4*)&o16[row + j0] = st;
        } else {
            float* of = (float*)outv;
            *(float4*)&of[row + j0] = a;
        }
    }
}

template <int MODE, int OUT16>
__global__ __launch_bounds__(256) void gemm128(const float* __restrict__ in,
                                               const float* __restrict__ W,
                                               const float* __restrict__ bias,
                                               const float* __restrict__ resid,
                                               const float* __restrict__ gamma,
                                               const float* __restrict__ beta,
                                               void* __restrict__ out) {
    gemm_body<MODE, OUT16>(in, W, bias, resid, gamma, beta, out);
}

__global__ __launch_bounds__(256) void gemm_qkv(const float* __restrict__ in,
                                                const float* __restrict__ wT,
                                                const float* __restrict__ bT,
                                                unsigned short* __restrict__ outb) {
    int y = blockIdx.y;
    gemm_body<1, 1>(in, wT + y * 16384, bT + y * 128, nullptr, nullptr, nullptr,
                    outb + (long)y * N_NODES * 128);
}

// ---------------- GCN aggregation (bf16 gather) + bias + LN + ReLU (+resid) ----------------
__global__ __launch_bounds__(128) void gcn_agg(const unsigned short* __restrict__ hW,
                                               const int* __restrict__ row_ptr,
                                               const int* __restrict__ srcs,
                                               const float* __restrict__ dis,
                                               const float* __restrict__ bias,
                                               const float* __restrict__ gamma,
                                               const float* __restrict__ beta,
                                               float* __restrict__ h, int with_resid) {
    int n = blockIdx.x, tid = threadIdx.x;
    __shared__ int sl[128];
    __shared__ float cl[128];
    __shared__ float red[4];
    int r0 = row_ptr[n], r1 = row_ptr[n + 1];
    float dn = dis[n];
    float acc = bf2f(hW[(long)n * 128 + tid]) * (dn * dn);   // self-loop
    for (int b = r0; b < r1; b += 128) {
        int cnt = min(128, r1 - b);
        if (tid < cnt) {
            int s = srcs[b + tid];
            sl[tid] = s;
            cl[tid] = dis[s] * dn;
        }
        __syncthreads();
        int i = 0;
        for (; i + 4 <= cnt; i += 4) {
            int s0 = sl[i], s1 = sl[i + 1], s2 = sl[i + 2], s3 = sl[i + 3];
            float a0 = bf2f(hW[(long)s0 * 128 + tid]);
            float a1 = bf2f(hW[(long)s1 * 128 + tid]);
            float a2 = bf2f(hW[(long)s2 * 128 + tid]);
            float a3 = bf2f(hW[(long)s3 * 128 + tid]);
            acc += a0 * cl[i] + a1 * cl[i + 1] + a2 * cl[i + 2] + a3 * cl[i + 3];
        }
        for (; i < cnt; i++) acc += bf2f(hW[(long)sl[i] * 128 + tid]) * cl[i];
        __syncthreads();
    }
    acc += bias[tid];
    float m, is;
    ln_stats128(acc, m, is, red);
    float y = (acc - m) * is * gamma[tid] + beta[tid];
    y = fmaxf(y, 0.f);
    if (with_resid) y += h[(long)n * 128 + tid];
    h[(long)n * 128 + tid] = y;
}

// ---------------- attention: MFMA (swapped QK^T) with scalar fallback ----------------
// grid dim3(G,NH), 256 threads. S^T tile = mfma(A=K, B=Q^T): D[key][query].
// D-layout == B-layout for 16x16x16 => exp'd P^T feeds PV mfma (A=V^T) with no
// cross-lane movement. O^T D-frag: col=query, row=d. exp2(s*0.25*log2e) folds scale.
__global__ __launch_bounds__(256) void attention(const unsigned short* __restrict__ q16,
                                                 const unsigned short* __restrict__ k16,
                                                 const unsigned short* __restrict__ v16,
                                                 float* __restrict__ o) {
    int g = blockIdx.x, hh = blockIdx.y;
    int tid = threadIdx.x;
    long gbase = ((long)g * NPG) * 128 + hh * 16;
#if defined(__HIP_DEVICE_COMPILE__) && defined(__has_builtin)
#if __has_builtin(__builtin_amdgcn_mfma_f32_16x16x16bf16_1k)
#define ATTN_MFMA 1
#endif
#endif
#ifdef ATTN_MFMA
    __shared__ unsigned short Ksh[256][24];   // padded rows: 48B, 16B-aligned
    __shared__ unsigned short Qsh[256][24];
    __shared__ unsigned short Vt[16][264];    // transposed V, padded
    {
        const unsigned short* kp = k16 + gbase + (long)tid * 128;
        uint4 a = *(const uint4*)kp, b = *(const uint4*)(kp + 8);
        *(uint4*)&Ksh[tid][0] = a; *(uint4*)&Ksh[tid][8] = b;
        const unsigned short* qp = q16 + gbase + (long)tid * 128;
        uint4 c = *(const uint4*)qp, d = *(const uint4*)(qp + 8);
        *(uint4*)&Qsh[tid][0] = c; *(uint4*)&Qsh[tid][8] = d;
        const unsigned short* vp = v16 + gbase + (long)tid * 128;
#pragma unroll
        for (int dd = 0; dd < 16; dd++) Vt[dd][tid] = vp[dd];
    }
    __syncthreads();
    int wv = tid >> 6, lane = tid & 63;
    int qg = lane >> 4, ql = lane & 15;
    // V^T A-frags: A[row=d=ql][k=4qg+j] of key-tile kt -> Vt[ql][16kt+4qg..+3]
    bf16x4 vfrag[16];
#pragma unroll
    for (int kt = 0; kt < 16; kt++)
        vfrag[kt] = *(const bf16x4*)&Vt[ql][kt * 16 + qg * 4];
    const float C = 0.36067376022224085f;   // 0.25 * log2(e)
    for (int qi = 0; qi < 4; qi++) {
        int qt = wv * 4 + qi;
        bf16x4 qfrag = *(const bf16x4*)&Qsh[qt * 16 + ql][qg * 4];
        float lsum = 0.f;
        bf16x4 pb[16];
        f32x4 z4 = {0.f, 0.f, 0.f, 0.f};
#pragma unroll
        for (int kt = 0; kt < 16; kt++) {
            bf16x4 kfrag = *(const bf16x4*)&Ksh[kt * 16 + ql][qg * 4];
            f32x4 s4 = __builtin_amdgcn_mfma_f32_16x16x16bf16_1k(kfrag, qfrag, z4, 0, 0, 0);
            bf16x4 pbk;
#pragma unroll
            for (int r = 0; r < 4; r++) {
                float pv = exp2f(s4[r] * C);
                lsum += pv;
                pbk[r] = (short)bfbits(pv);
            }
            pb[kt] = pbk;
        }
        f32x4 oacc = {0.f, 0.f, 0.f, 0.f};
#pragma unroll
        for (int kt = 0; kt < 16; kt++)
            oacc = __builtin_amdgcn_mfma_f32_16x16x16bf16_1k(vfrag[kt], pb[kt], oacc, 0, 0, 0);
        lsum += __shfl_xor(lsum, 16);
        lsum += __shfl_xor(lsum, 32);
        float inv = 1.f / lsum;
        float* op = o + gbase + (long)(qt * 16 + ql) * 128 + 4 * qg;
        *(float4*)op = make_float4(oacc[0] * inv, oacc[1] * inv, oacc[2] * inv, oacc[3] * inv);
    }
#else
    // scalar fallback (bf16 inputs, no-max softmax)
    __shared__ float ks[NPG * DH];
    __shared__ float vs[NPG * DH];
    for (int idx = tid; idx < NPG * DH; idx += 256) {
        int r = idx >> 4, d = idx & 15;
        ks[idx] = bf2f(k16[gbase + (long)r * 128 + d]);
        vs[idx] = bf2f(v16[gbase + (long)r * 128 + d]);
    }
    __syncthreads();
    float qr[16];
    const unsigned short* qp = q16 + gbase + (long)tid * 128;
#pragma unroll
    for (int d = 0; d < 16; d++) qr[d] = bf2f(qp[d]) * 0.36067376022224085f;
    float l = 0.f, acc[16];
#pragma unroll
    for (int d = 0; d < 16; d++) acc[d] = 0.f;
#pragma unroll 2
    for (int j = 0; j < NPG; j++) {
        float s = 0.f;
#pragma unroll
        for (int d = 0; d < 16; d++) s += qr[d] * ks[j * 16 + d];
        float p = exp2f(s);
        l += p;
#pragma unroll
        for (int d = 0; d < 16; d++) acc[d] += p * vs[j * 16 + d];
    }
    float inv = 1.f / l;
    float* op = o + gbase + (long)tid * 128;
#pragma unroll
    for (int d = 0; d < 16; d++) op[d] = acc[d] * inv;
#endif
}

// ---------------- pooling: mean/max/sum per graph ----------------
__global__ __launch_bounds__(512) void pool_kernel(const float* __restrict__ hg,
                                                   float* __restrict__ pooled) {
    int g = blockIdx.x;
    int tid = threadIdx.x;
    int j = tid & 127, grp = tid >> 7;
    __shared__ float ssum[4][128];
    __shared__ float smax[4][128];
    float s = 0.f, mx = -1e30f;
    for (int i = grp * 64; i < grp * 64 + 64; i++) {
        float vv = hg[((long)g * NPG + i) * 128 + j];
        s += vv;
        mx = fmaxf(mx, vv);
    }
    ssum[grp][j] = s;
    smax[grp][j] = mx;
    __syncthreads();
    if (grp == 0) {
        float ts = ssum[0][j] + ssum[1][j] + ssum[2][j] + ssum[3][j];
        float tm = fmaxf(fmaxf(smax[0][j], smax[1][j]), fmaxf(smax[2][j], smax[3][j]));
        pooled[g * 384 + j] = ts * (1.f / 256.f);
        pooled[g * 384 + 128 + j] = tm;
        pooled[g * 384 + 256 + j] = ts;
    }
}

// ---------------- classifier ----------------
__global__ __launch_bounds__(128) void classifier(const float* __restrict__ pooled,
                                                  const float* __restrict__ W1, const float* __restrict__ b1,
                                                  const float* __restrict__ g1, const float* __restrict__ be1,
                                                  const float* __restrict__ W2, const float* __restrict__ b2,
                                                  const float* __restrict__ W3, const float* __restrict__ b3,
                                                  float* __restrict__ out) {
    int g = blockIdx.x, j = threadIdx.x;
    __shared__ float pl[384];
    __shared__ float z1s[128];
    __shared__ float z2s[64];
    __shared__ float red[4];
    for (int i = j; i < 384; i += 128) pl[i] = pooled[g * 384 + i];
    __syncthreads();
    float acc = b1[j];
    for (int kk = 0; kk < 384; kk++) acc += pl[kk] * W1[kk * 128 + j];
    float m, is;
    ln_stats128(acc, m, is, red);
    float y = fmaxf((acc - m) * is * g1[j] + be1[j], 0.f);
    z1s[j] = y;
    __syncthreads();
    if (j < 64) {
        float a2 = b2[j];
        for (int kk = 0; kk < 128; kk++) a2 += z1s[kk] * W2[kk * 64 + j];
        z2s[j] = fmaxf(a2, 0.f);
    }
    __syncthreads();
    if (j < 64) {
        float vv = z2s[j];
        float p0 = vv * W3[j * 2];
        float p1 = vv * W3[j * 2 + 1];
#pragma unroll
        for (int off = 32; off; off >>= 1) { p0 += __shfl_xor(p0, off); p1 += __shfl_xor(p1, off); }
        if (j == 0) {
            out[g * 2] = p0 + b3[0];
            out[g * 2 + 1] = p1 + b3[1];
        }
    }
}

// ---------------- launch ----------------
extern "C" void kernel_launch(void* const* d_in, const int* in_sizes, int n_in,
                              void* d_out, int out_size, void* d_ws, size_t ws_size,
                              hipStream_t stream) {
    const float* x = (const float*)d_in[0];
    const int* ei = (const int*)d_in[1];       // [2, E]: src then dst
    const float* W_in = (const float*)d_in[3];
    const float* b_in = (const float*)d_in[4];
    const float* g_in = (const float*)d_in[5];
    const float* be_in = (const float*)d_in[6];
    const float* Wc = (const float*)d_in[7];   // [3,128,128]
    const float* bc = (const float*)d_in[8];
    const float* gn = (const float*)d_in[9];
    const float* bn = (const float*)d_in[10];
    const float* Wq = (const float*)d_in[11];
    const float* bq = (const float*)d_in[12];
    const float* Wk = (const float*)d_in[13];
    const float* bk = (const float*)d_in[14];
    const float* Wv = (const float*)d_in[15];
    const float* bv = (const float*)d_in[16];
    const float* Wo = (const float*)d_in[17];
    const float* bo = (const float*)d_in[18];
    const float* ga = (const float*)d_in[19];
    const float* ba = (const float*)d_in[20];
    const float* W1 = (const float*)d_in[21];
    const float* b1 = (const float*)d_in[22];
    const float* g1 = (const float*)d_in[23];
    const float* be1 = (const float*)d_in[24];
    const float* W2 = (const float*)d_in[25];
    const float* b2 = (const float*)d_in[26];
    const float* W3 = (const float*)d_in[27];
    const float* b3 = (const float*)d_in[28];
    float* out = (float*)d_out;

    const long NF = (long)N_NODES * 128;
    float* ws = (float*)d_ws;
    float* h = ws;                              // [N,128] fp32
    unsigned short* hw16 = (unsigned short*)(ws + NF);   // [N,128] bf16 (GCN hW)
    float* hg2 = ws + NF;                       // reuses hw16 region post-GCN
    float* obuf = ws + 2 * NF;                  // attention output, fp32
    unsigned short* qkv16 = (unsigned short*)(ws + 3 * NF);  // 3x[N,128] bf16 (1.5NF floats)
    float* dis = ws + 5 * NF;                   // [N]
    float* pooled = dis + N_NODES;              // [G,384]
    float* wT = pooled + G_GRAPHS * 384;        // 4 x 16384
    float* bT = wT + 4 * 16384;                 // 3 x 128
    int* ib = (int*)(bT + 3 * 128);
    int* counts = ib;                           // [N]
    int* fill = ib + N_NODES;                   // [N]
    int* srcs = ib + 2 * N_NODES;               // [E]
    int* row_ptr = srcs + E_EDGES;              // [N+1]

    const int* e_src = ei;
    const int* e_dst = ei + E_EDGES;

    hipMemsetAsync(counts, 0, N_NODES * sizeof(int), stream);
    transpose4<<<dim3(64, 4), 256, 0, stream>>>(Wq, Wk, Wv, Wo, bq, bk, bv, wT, bT);
    hist_kernel<<<E_EDGES / 256, 256, 0, stream>>>(e_dst, counts);
    scan_kernel<<<1, 1024, 0, stream>>>(counts, row_ptr, fill, dis);
    scatter_kernel<<<E_EDGES / 256, 256, 0, stream>>>(e_src, e_dst, fill, srcs);

    input_proj<<<N_NODES, 128, 0, stream>>>(x, W_in, b_in, g_in, be_in, h);

    for (int i = 0; i < 3; i++) {
        gemm128<0, 1><<<N_NODES / 64, 256, 0, stream>>>(h, Wc + i * 16384, nullptr, nullptr,
                                                        nullptr, nullptr, hw16);
        gcn_agg<<<N_NODES, 128, 0, stream>>>(hw16, row_ptr, srcs, dis, bc + i * 128,
                                             gn + i * 128, bn + i * 128, h, i > 0);
    }

    gemm_qkv<<<dim3(N_NODES / 64, 3), 256, 0, stream>>>(h, wT, bT, qkv16);

    attention<<<dim3(G_GRAPHS, NH), 256, 0, stream>>>(qkv16, qkv16 + NF, qkv16 + 2 * NF, obuf);

    gemm128<2, 0><<<N_NODES / 64, 256, 0, stream>>>(obuf, wT + 3 * 16384, bo, h, ga, ba, hg2);

    pool_kernel<<<G_GRAPHS, 512, 0, stream>>>(hg2, pooled);
    classifier<<<G_GRAPHS, 128, 0, stream>>>(pooled, W1, b1, g1, be1, W2, b2, W3, b3, out);
}

// Round 4
// 493.039 us; speedup vs baseline: 1.5122x; 1.2115x over previous
//
#include <hip/hip_runtime.h>
#include <hip/hip_bf16.h>

#define N_NODES 32768
#define E_EDGES 1048576
#define HID 128
#define G_GRAPHS 128
#define NPG 256
#define NH 8
#define DH 16
#define EPS 1e-5f
#define CHUNK 4096
#define BCAP 8192

typedef __attribute__((ext_vector_type(4))) float f32x4;
typedef __attribute__((ext_vector_type(4))) short bf16x4;

static __device__ __forceinline__ unsigned short bfbits(float f) {
    return __builtin_bit_cast(unsigned short, __float2bfloat16(f));
}
static __device__ __forceinline__ float bf2f(unsigned short u) {
    return __builtin_bit_cast(float, (unsigned)u << 16);
}

// ---------------- helpers ----------------
__device__ __forceinline__ void ln_stats128(float v, float& mean, float& istd, float* red) {
    float s = v, s2 = v * v;
#pragma unroll
    for (int off = 32; off; off >>= 1) { s += __shfl_xor(s, off); s2 += __shfl_xor(s2, off); }
    int w = threadIdx.x >> 6;
    if ((threadIdx.x & 63) == 0) { red[w * 2] = s; red[w * 2 + 1] = s2; }
    __syncthreads();
    float ts = red[0] + red[2], ts2 = red[1] + red[3];
    mean = ts * (1.f / 128.f);
    float var = ts2 * (1.f / 128.f) - mean * mean;
    istd = rsqrtf(var + EPS);
    __syncthreads();
}

// ---------------- CSR build: bucketed counting sort ----------------
// bucket b = dst>>7 (256 buckets x 128 nodes). Single-writer-block per region
// kills the cross-XCD line-sharing write amplification the old scatter had.
__global__ __launch_bounds__(256) void bucket_count(const int* __restrict__ dst,
                                                    int* __restrict__ bucket_cnt) {
    __shared__ int bcnt[256];
    int tid = threadIdx.x;
    bcnt[tid] = 0;
    __syncthreads();
    int base = blockIdx.x * CHUNK;
#pragma unroll
    for (int j = 0; j < 16; j++) {
        int d = dst[base + j * 256 + tid];
        atomicAdd(&bcnt[d >> 7], 1);
    }
    __syncthreads();
    atomicAdd(&bucket_cnt[tid], bcnt[tid]);
}

__global__ __launch_bounds__(256) void scan_buckets(const int* __restrict__ bucket_cnt,
                                                    int* __restrict__ bucket_base,
                                                    int* __restrict__ bucket_fill) {
    __shared__ int sc[256];
    int t = threadIdx.x;
    int c = bucket_cnt[t];
    sc[t] = c;
    __syncthreads();
    for (int off = 1; off < 256; off <<= 1) {
        int v = (t >= off) ? sc[t - off] : 0;
        __syncthreads();
        sc[t] += v;
        __syncthreads();
    }
    int ex = sc[t] - c;
    bucket_base[t] = ex;
    bucket_fill[t] = ex;
    if (t == 255) bucket_base[256] = sc[255];
}

__global__ __launch_bounds__(256) void bucket_scatter(const int* __restrict__ src,
                                                      const int* __restrict__ dst,
                                                      int* __restrict__ bucket_fill,
                                                      int* __restrict__ packed) {
    __shared__ int bcnt[256];
    __shared__ int lsc[256];
    __shared__ int delta[256];
    __shared__ int sorted[CHUNK];
    int tid = threadIdx.x;
    int base = blockIdx.x * CHUNK;
    int pk[16], bk[16], rk[16];
    bcnt[tid] = 0;
    __syncthreads();
#pragma unroll
    for (int j = 0; j < 16; j++) {
        int e = base + j * 256 + tid;    // coalesced
        int d = dst[e], s = src[e];
        pk[j] = (d << 15) | s;           // 30 bits
        bk[j] = d >> 7;
    }
#pragma unroll
    for (int j = 0; j < 16; j++) rk[j] = atomicAdd(&bcnt[bk[j]], 1);
    __syncthreads();
    int cnt_t = bcnt[tid];
    lsc[tid] = cnt_t;
    __syncthreads();
    for (int off = 1; off < 256; off <<= 1) {
        int v = (tid >= off) ? lsc[tid - off] : 0;
        __syncthreads();
        lsc[tid] += v;
        __syncthreads();
    }
    int ls_t = lsc[tid] - cnt_t;   // exclusive
    __syncthreads();
    lsc[tid] = ls_t;
    int g = 0;
    if (cnt_t > 0) g = atomicAdd(&bucket_fill[tid], cnt_t);
    delta[tid] = g - ls_t;
    __syncthreads();
#pragma unroll
    for (int j = 0; j < 16; j++) sorted[lsc[bk[j]] + rk[j]] = pk[j];
    __syncthreads();
    for (int i = tid; i < CHUNK; i += 256) {
        int u = sorted[i];
        int b2 = u >> 22;              // = dst>>7
        packed[delta[b2] + i] = u;     // runs of ~16 -> mostly coalesced
    }
}

__global__ __launch_bounds__(256) void csr_build(const int* __restrict__ bucket_base,
                                                 const int* __restrict__ packed,
                                                 int* __restrict__ srcs,
                                                 int* __restrict__ row_ptr,
                                                 float* __restrict__ dis) {
    __shared__ int ncnt[128];
    __shared__ int sc[128];
    __shared__ int fill[128];
    __shared__ int outl[BCAP];
    int b = blockIdx.x, tid = threadIdx.x;
    int c0 = bucket_base[b], c1 = bucket_base[b + 1];
    int cnt = c1 - c0;
    if (tid < 128) ncnt[tid] = 0;
    __syncthreads();
    for (int i = tid; i < cnt; i += 256) {
        int u = packed[c0 + i];
        atomicAdd(&ncnt[(u >> 15) & 127], 1);
    }
    __syncthreads();
    int c = (tid < 128) ? ncnt[tid] : 0;
    if (tid < 128) sc[tid] = c;
    __syncthreads();
    for (int off = 1; off < 128; off <<= 1) {
        int v = (tid < 128 && tid >= off) ? sc[tid - off] : 0;
        __syncthreads();
        if (tid < 128) sc[tid] += v;
        __syncthreads();
    }
    if (tid < 128) {
        int ex = sc[tid] - c;
        fill[tid] = ex;
        int node = b * 128 + tid;
        row_ptr[node] = c0 + ex;
        dis[node] = rsqrtf((float)(c + 1));   // deg includes self-loop
    }
    if (b == 255 && tid == 0) row_ptr[N_NODES] = c1;
    __syncthreads();
    if (cnt <= BCAP) {
        for (int i = tid; i < cnt; i += 256) {
            int u = packed[c0 + i];
            int p = atomicAdd(&fill[(u >> 15) & 127], 1);
            outl[p] = u & 32767;
        }
        __syncthreads();
        for (int i = tid; i < cnt; i += 256) srcs[c0 + i] = outl[i];  // coalesced
    } else {
        // fallback (still correct; single-writer region keeps it L2-local)
        for (int i = tid; i < cnt; i += 256) {
            int u = packed[c0 + i];
            int p = atomicAdd(&fill[(u >> 15) & 127], 1);
            srcs[c0 + p] = u & 32767;
        }
    }
}

// ---------------- weight transpose + bias staging ----------------
__global__ void transpose4(const float* __restrict__ Wq, const float* __restrict__ Wk,
                           const float* __restrict__ Wv, const float* __restrict__ Wo,
                           const float* __restrict__ bq, const float* __restrict__ bk,
                           const float* __restrict__ bv,
                           float* __restrict__ out, float* __restrict__ bT) {
    int i = blockIdx.x * 256 + threadIdx.x;   // 0..16383
    int w = blockIdx.y;
    const float* src = (w == 0) ? Wq : (w == 1) ? Wk : (w == 2) ? Wv : Wo;
    int k = i >> 7, j = i & 127;
    out[w * 16384 + i] = src[j * 128 + k];    // WT[k][j] = W[j][k]
    if (w < 3 && i < 128) {
        const float* bs = (w == 0) ? bq : (w == 1) ? bk : bv;
        bT[w * 128 + i] = bs[i];
    }
}

// ---------------- input projection + LN + ReLU ----------------
__global__ __launch_bounds__(128) void input_proj(const float* __restrict__ x,
                                                  const float* __restrict__ W,
                                                  const float* __restrict__ b,
                                                  const float* __restrict__ g,
                                                  const float* __restrict__ be,
                                                  float* __restrict__ h) {
    int n = blockIdx.x, j = threadIdx.x;
    __shared__ float xs[15];
    __shared__ float red[4];
    if (j < 15) xs[j] = x[n * 15 + j];
    __syncthreads();
    float acc = b[j];
#pragma unroll
    for (int k = 0; k < 15; k++) acc += xs[k] * W[k * 128 + j];
    float m, is;
    ln_stats128(acc, m, is, red);
    float y = (acc - m) * is * g[j] + be[j];
    h[(long)n * 128 + j] = fmaxf(y, 0.f);
}

// ---------------- 128-wide GEMM body ----------------
// MODE 0: plain.  MODE 1: +bias.  MODE 2: +bias +resid, then LN(gamma,beta).
// OUT16: write bf16 (ushort) instead of fp32.
template <int MODE, int OUT16>
__device__ __forceinline__ void gemm_body(const float* __restrict__ in,
                                          const float* __restrict__ W,
                                          const float* __restrict__ bias,
                                          const float* __restrict__ resid,
                                          const float* __restrict__ gamma,
                                          const float* __restrict__ beta,
                                          void* __restrict__ outv) {
    __shared__ float Wl[32 * 128];
    __shared__ float hl[64 * 32];
    int tid = threadIdx.x;
    int jq = tid & 31;
    int oct = tid >> 5;
    long base = (long)blockIdx.x * 64;

    float4 acc[8];
#pragma unroll
    for (int i = 0; i < 8; i++) acc[i] = make_float4(0.f, 0.f, 0.f, 0.f);

    for (int kc = 0; kc < 4; kc++) {
        const float4* Wv4 = (const float4*)(W + kc * 32 * 128);
        float4* Wl4 = (float4*)Wl;
        for (int i = tid; i < 1024; i += 256) Wl4[i] = Wv4[i];
        const float* inb = in + base * 128 + kc * 32;
        for (int i = tid; i < 512; i += 256) {
            int n = i >> 3, c4 = i & 7;
            *(float4*)&hl[n * 32 + c4 * 4] = *(const float4*)&inb[n * 128 + c4 * 4];
        }
        __syncthreads();
#pragma unroll
        for (int kk = 0; kk < 32; kk++) {
            float4 w4 = *(float4*)&Wl[kk * 128 + jq * 4];
#pragma unroll
            for (int n8 = 0; n8 < 8; n8++) {
                float hv = hl[(oct * 8 + n8) * 32 + kk];
                acc[n8].x += hv * w4.x;
                acc[n8].y += hv * w4.y;
                acc[n8].z += hv * w4.z;
                acc[n8].w += hv * w4.w;
            }
        }
        __syncthreads();
    }

    int j0 = jq * 4;
#pragma unroll
    for (int n8 = 0; n8 < 8; n8++) {
        long row = (base + oct * 8 + n8) * 128;
        float4 a = acc[n8];
        if (MODE >= 1) {
            float4 b4 = *(const float4*)&bias[j0];
            a.x += b4.x; a.y += b4.y; a.z += b4.z; a.w += b4.w;
        }
        if (MODE == 2) {
            float4 r4 = *(const float4*)&resid[row + j0];
            a.x += r4.x; a.y += r4.y; a.z += r4.z; a.w += r4.w;
            float s = a.x + a.y + a.z + a.w;
            float s2 = a.x * a.x + a.y * a.y + a.z * a.z + a.w * a.w;
#pragma unroll
            for (int off = 16; off; off >>= 1) { s += __shfl_xor(s, off); s2 += __shfl_xor(s2, off); }
            float mean = s * (1.f / 128.f);
            float var = s2 * (1.f / 128.f) - mean * mean;
            float is = rsqrtf(var + EPS);
            float4 g4 = *(const float4*)&gamma[j0];
            float4 be4 = *(const float4*)&beta[j0];
            a.x = (a.x - mean) * is * g4.x + be4.x;
            a.y = (a.y - mean) * is * g4.y + be4.y;
            a.z = (a.z - mean) * is * g4.z + be4.z;
            a.w = (a.w - mean) * is * g4.w + be4.w;
        }
        if (OUT16) {
            unsigned short* o16 = (unsigned short*)outv;
            ushort4 st;
            st.x = bfbits(a.x); st.y = bfbits(a.y); st.z = bfbits(a.z); st.w = bfbits(a.w);
            *(ushort4*)&o16[row + j0] = st;
        } else {
            float* of = (float*)outv;
            *(float4*)&of[row + j0] = a;
        }
    }
}

template <int MODE, int OUT16>
__global__ __launch_bounds__(256) void gemm128(const float* __restrict__ in,
                                               const float* __restrict__ W,
                                               const float* __restrict__ bias,
                                               const float* __restrict__ resid,
                                               const float* __restrict__ gamma,
                                               const float* __restrict__ beta,
                                               void* __restrict__ out) {
    gemm_body<MODE, OUT16>(in, W, bias, resid, gamma, beta, out);
}

__global__ __launch_bounds__(256) void gemm_qkv(const float* __restrict__ in,
                                                const float* __restrict__ wT,
                                                const float* __restrict__ bT,
                                                unsigned short* __restrict__ outb) {
    int y = blockIdx.y;
    gemm_body<1, 1>(in, wT + y * 16384, bT + y * 128, nullptr, nullptr, nullptr,
                    outb + (long)y * N_NODES * 128);
}

// ---------------- GCN aggregation (bf16 gather) + bias + LN + ReLU (+resid) ----------------
__global__ __launch_bounds__(128) void gcn_agg(const unsigned short* __restrict__ hW,
                                               const int* __restrict__ row_ptr,
                                               const int* __restrict__ srcs,
                                               const float* __restrict__ dis,
                                               const float* __restrict__ bias,
                                               const float* __restrict__ gamma,
                                               const float* __restrict__ beta,
                                               float* __restrict__ h, int with_resid) {
    int n = blockIdx.x, tid = threadIdx.x;
    __shared__ int sl[128];
    __shared__ float cl[128];
    __shared__ float red[4];
    int r0 = row_ptr[n], r1 = row_ptr[n + 1];
    float dn = dis[n];
    float acc = bf2f(hW[(long)n * 128 + tid]) * (dn * dn);   // self-loop
    for (int b = r0; b < r1; b += 128) {
        int cnt = min(128, r1 - b);
        if (tid < cnt) {
            int s = srcs[b + tid];
            sl[tid] = s;
            cl[tid] = dis[s] * dn;
        }
        __syncthreads();
        int i = 0;
        for (; i + 4 <= cnt; i += 4) {
            int s0 = sl[i], s1 = sl[i + 1], s2 = sl[i + 2], s3 = sl[i + 3];
            float a0 = bf2f(hW[(long)s0 * 128 + tid]);
            float a1 = bf2f(hW[(long)s1 * 128 + tid]);
            float a2 = bf2f(hW[(long)s2 * 128 + tid]);
            float a3 = bf2f(hW[(long)s3 * 128 + tid]);
            acc += a0 * cl[i] + a1 * cl[i + 1] + a2 * cl[i + 2] + a3 * cl[i + 3];
        }
        for (; i < cnt; i++) acc += bf2f(hW[(long)sl[i] * 128 + tid]) * cl[i];
        __syncthreads();
    }
    acc += bias[tid];
    float m, is;
    ln_stats128(acc, m, is, red);
    float y = (acc - m) * is * gamma[tid] + beta[tid];
    y = fmaxf(y, 0.f);
    if (with_resid) y += h[(long)n * 128 + tid];
    h[(long)n * 128 + tid] = y;
}

// ---------------- attention: MFMA (swapped QK^T) with scalar fallback ----------------
__global__ __launch_bounds__(256) void attention(const unsigned short* __restrict__ q16,
                                                 const unsigned short* __restrict__ k16,
                                                 const unsigned short* __restrict__ v16,
                                                 float* __restrict__ o) {
    int g = blockIdx.x, hh = blockIdx.y;
    int tid = threadIdx.x;
    long gbase = ((long)g * NPG) * 128 + hh * 16;
#if defined(__HIP_DEVICE_COMPILE__) && defined(__has_builtin)
#if __has_builtin(__builtin_amdgcn_mfma_f32_16x16x16bf16_1k)
#define ATTN_MFMA 1
#endif
#endif
#ifdef ATTN_MFMA
    __shared__ unsigned short Ksh[256][24];
    __shared__ unsigned short Qsh[256][24];
    __shared__ unsigned short Vt[16][264];
    {
        const unsigned short* kp = k16 + gbase + (long)tid * 128;
        uint4 a = *(const uint4*)kp, b = *(const uint4*)(kp + 8);
        *(uint4*)&Ksh[tid][0] = a; *(uint4*)&Ksh[tid][8] = b;
        const unsigned short* qp = q16 + gbase + (long)tid * 128;
        uint4 c = *(const uint4*)qp, d = *(const uint4*)(qp + 8);
        *(uint4*)&Qsh[tid][0] = c; *(uint4*)&Qsh[tid][8] = d;
        const unsigned short* vp = v16 + gbase + (long)tid * 128;
#pragma unroll
        for (int dd = 0; dd < 16; dd++) Vt[dd][tid] = vp[dd];
    }
    __syncthreads();
    int wv = tid >> 6, lane = tid & 63;
    int qg = lane >> 4, ql = lane & 15;
    bf16x4 vfrag[16];
#pragma unroll
    for (int kt = 0; kt < 16; kt++)
        vfrag[kt] = *(const bf16x4*)&Vt[ql][kt * 16 + qg * 4];
    const float C = 0.36067376022224085f;   // 0.25 * log2(e)
    for (int qi = 0; qi < 4; qi++) {
        int qt = wv * 4 + qi;
        bf16x4 qfrag = *(const bf16x4*)&Qsh[qt * 16 + ql][qg * 4];
        float lsum = 0.f;
        bf16x4 pb[16];
        f32x4 z4 = {0.f, 0.f, 0.f, 0.f};
#pragma unroll
        for (int kt = 0; kt < 16; kt++) {
            bf16x4 kfrag = *(const bf16x4*)&Ksh[kt * 16 + ql][qg * 4];
            f32x4 s4 = __builtin_amdgcn_mfma_f32_16x16x16bf16_1k(kfrag, qfrag, z4, 0, 0, 0);
            bf16x4 pbk;
#pragma unroll
            for (int r = 0; r < 4; r++) {
                float pv = exp2f(s4[r] * C);
                lsum += pv;
                pbk[r] = (short)bfbits(pv);
            }
            pb[kt] = pbk;
        }
        f32x4 oacc = {0.f, 0.f, 0.f, 0.f};
#pragma unroll
        for (int kt = 0; kt < 16; kt++)
            oacc = __builtin_amdgcn_mfma_f32_16x16x16bf16_1k(vfrag[kt], pb[kt], oacc, 0, 0, 0);
        lsum += __shfl_xor(lsum, 16);
        lsum += __shfl_xor(lsum, 32);
        float inv = 1.f / lsum;
        float* op = o + gbase + (long)(qt * 16 + ql) * 128 + 4 * qg;
        *(float4*)op = make_float4(oacc[0] * inv, oacc[1] * inv, oacc[2] * inv, oacc[3] * inv);
    }
#else
    __shared__ float ks[NPG * DH];
    __shared__ float vs[NPG * DH];
    for (int idx = tid; idx < NPG * DH; idx += 256) {
        int r = idx >> 4, d = idx & 15;
        ks[idx] = bf2f(k16[gbase + (long)r * 128 + d]);
        vs[idx] = bf2f(v16[gbase + (long)r * 128 + d]);
    }
    __syncthreads();
    float qr[16];
    const unsigned short* qp = q16 + gbase + (long)tid * 128;
#pragma unroll
    for (int d = 0; d < 16; d++) qr[d] = bf2f(qp[d]) * 0.36067376022224085f;
    float l = 0.f, acc[16];
#pragma unroll
    for (int d = 0; d < 16; d++) acc[d] = 0.f;
#pragma unroll 2
    for (int j = 0; j < NPG; j++) {
        float s = 0.f;
#pragma unroll
        for (int d = 0; d < 16; d++) s += qr[d] * ks[j * 16 + d];
        float p = exp2f(s);
        l += p;
#pragma unroll
        for (int d = 0; d < 16; d++) acc[d] += p * vs[j * 16 + d];
    }
    float inv = 1.f / l;
    float* op = o + gbase + (long)tid * 128;
#pragma unroll
    for (int d = 0; d < 16; d++) op[d] = acc[d] * inv;
#endif
}

// ---------------- pooling: mean/max/sum per graph ----------------
__global__ __launch_bounds__(512) void pool_kernel(const float* __restrict__ hg,
                                                   float* __restrict__ pooled) {
    int g = blockIdx.x;
    int tid = threadIdx.x;
    int j = tid & 127, grp = tid >> 7;
    __shared__ float ssum[4][128];
    __shared__ float smax[4][128];
    float s = 0.f, mx = -1e30f;
    for (int i = grp * 64; i < grp * 64 + 64; i++) {
        float vv = hg[((long)g * NPG + i) * 128 + j];
        s += vv;
        mx = fmaxf(mx, vv);
    }
    ssum[grp][j] = s;
    smax[grp][j] = mx;
    __syncthreads();
    if (grp == 0) {
        float ts = ssum[0][j] + ssum[1][j] + ssum[2][j] + ssum[3][j];
        float tm = fmaxf(fmaxf(smax[0][j], smax[1][j]), fmaxf(smax[2][j], smax[3][j]));
        pooled[g * 384 + j] = ts * (1.f / 256.f);
        pooled[g * 384 + 128 + j] = tm;
        pooled[g * 384 + 256 + j] = ts;
    }
}

// ---------------- classifier ----------------
__global__ __launch_bounds__(128) void classifier(const float* __restrict__ pooled,
                                                  const float* __restrict__ W1, const float* __restrict__ b1,
                                                  const float* __restrict__ g1, const float* __restrict__ be1,
                                                  const float* __restrict__ W2, const float* __restrict__ b2,
                                                  const float* __restrict__ W3, const float* __restrict__ b3,
                                                  float* __restrict__ out) {
    int g = blockIdx.x, j = threadIdx.x;
    __shared__ float pl[384];
    __shared__ float z1s[128];
    __shared__ float z2s[64];
    __shared__ float red[4];
    for (int i = j; i < 384; i += 128) pl[i] = pooled[g * 384 + i];
    __syncthreads();
    float acc = b1[j];
    for (int kk = 0; kk < 384; kk++) acc += pl[kk] * W1[kk * 128 + j];
    float m, is;
    ln_stats128(acc, m, is, red);
    float y = fmaxf((acc - m) * is * g1[j] + be1[j], 0.f);
    z1s[j] = y;
    __syncthreads();
    if (j < 64) {
        float a2 = b2[j];
        for (int kk = 0; kk < 128; kk++) a2 += z1s[kk] * W2[kk * 64 + j];
        z2s[j] = fmaxf(a2, 0.f);
    }
    __syncthreads();
    if (j < 64) {
        float vv = z2s[j];
        float p0 = vv * W3[j * 2];
        float p1 = vv * W3[j * 2 + 1];
#pragma unroll
        for (int off = 32; off; off >>= 1) { p0 += __shfl_xor(p0, off); p1 += __shfl_xor(p1, off); }
        if (j == 0) {
            out[g * 2] = p0 + b3[0];
            out[g * 2 + 1] = p1 + b3[1];
        }
    }
}

// ---------------- launch ----------------
extern "C" void kernel_launch(void* const* d_in, const int* in_sizes, int n_in,
                              void* d_out, int out_size, void* d_ws, size_t ws_size,
                              hipStream_t stream) {
    const float* x = (const float*)d_in[0];
    const int* ei = (const int*)d_in[1];       // [2, E]: src then dst
    const float* W_in = (const float*)d_in[3];
    const float* b_in = (const float*)d_in[4];
    const float* g_in = (const float*)d_in[5];
    const float* be_in = (const float*)d_in[6];
    const float* Wc = (const float*)d_in[7];   // [3,128,128]
    const float* bc = (const float*)d_in[8];
    const float* gn = (const float*)d_in[9];
    const float* bn = (const float*)d_in[10];
    const float* Wq = (const float*)d_in[11];
    const float* bq = (const float*)d_in[12];
    const float* Wk = (const float*)d_in[13];
    const float* bk = (const float*)d_in[14];
    const float* Wv = (const float*)d_in[15];
    const float* bv = (const float*)d_in[16];
    const float* Wo = (const float*)d_in[17];
    const float* bo = (const float*)d_in[18];
    const float* ga = (const float*)d_in[19];
    const float* ba = (const float*)d_in[20];
    const float* W1 = (const float*)d_in[21];
    const float* b1 = (const float*)d_in[22];
    const float* g1 = (const float*)d_in[23];
    const float* be1 = (const float*)d_in[24];
    const float* W2 = (const float*)d_in[25];
    const float* b2 = (const float*)d_in[26];
    const float* W3 = (const float*)d_in[27];
    const float* b3 = (const float*)d_in[28];
    float* out = (float*)d_out;

    const long NF = (long)N_NODES * 128;
    float* ws = (float*)d_ws;
    float* h = ws;                              // [N,128] fp32
    unsigned short* hw16 = (unsigned short*)(ws + NF);   // [N,128] bf16 (GCN hW)
    float* hg2 = ws + NF;                       // reuses hw16 region post-GCN
    float* obuf = ws + 2 * NF;                  // attention output, fp32
    unsigned short* qkv16 = (unsigned short*)(ws + 3 * NF);  // 3x[N,128] bf16 = 1.5NF floats
    int* packed = (int*)(ws + 9 * NF / 2);      // [E] ints (fits in 0.5NF floats)
    float* dis = ws + 5 * NF;                   // [N]
    float* pooled = dis + N_NODES;              // [G,384]
    float* wT = pooled + G_GRAPHS * 384;        // 4 x 16384
    float* bT = wT + 4 * 16384;                 // 3 x 128
    int* ib = (int*)(bT + 3 * 128);
    int* bucket_cnt = ib;                       // [256]
    int* bucket_base = ib + 256;                // [257]
    int* bucket_fill = ib + 513;                // [256]
    int* srcs = ib + 769;                       // [E]
    int* row_ptr = srcs + E_EDGES;              // [N+1]

    const int* e_src = ei;
    const int* e_dst = ei + E_EDGES;

    hipMemsetAsync(bucket_cnt, 0, 256 * sizeof(int), stream);
    transpose4<<<dim3(64, 4), 256, 0, stream>>>(Wq, Wk, Wv, Wo, bq, bk, bv, wT, bT);
    bucket_count<<<E_EDGES / CHUNK, 256, 0, stream>>>(e_dst, bucket_cnt);
    scan_buckets<<<1, 256, 0, stream>>>(bucket_cnt, bucket_base, bucket_fill);
    bucket_scatter<<<E_EDGES / CHUNK, 256, 0, stream>>>(e_src, e_dst, bucket_fill, packed);
    csr_build<<<256, 256, 0, stream>>>(bucket_base, packed, srcs, row_ptr, dis);

    input_proj<<<N_NODES, 128, 0, stream>>>(x, W_in, b_in, g_in, be_in, h);

    for (int i = 0; i < 3; i++) {
        gemm128<0, 1><<<N_NODES / 64, 256, 0, stream>>>(h, Wc + i * 16384, nullptr, nullptr,
                                                        nullptr, nullptr, hw16);
        gcn_agg<<<N_NODES, 128, 0, stream>>>(hw16, row_ptr, srcs, dis, bc + i * 128,
                                             gn + i * 128, bn + i * 128, h, i > 0);
    }

    gemm_qkv<<<dim3(N_NODES / 64, 3), 256, 0, stream>>>(h, wT, bT, qkv16);

    attention<<<dim3(G_GRAPHS, NH), 256, 0, stream>>>(qkv16, qkv16 + NF, qkv16 + 2 * NF, obuf);

    gemm128<2, 0><<<N_NODES / 64, 256, 0, stream>>>(obuf, wT + 3 * 16384, bo, h, ga, ba, hg2);

    pool_kernel<<<G_GRAPHS, 512, 0, stream>>>(hg2, pooled);
    classifier<<<G_GRAPHS, 128, 0, stream>>>(pooled, W1, b1, g1, be1, W2, b2, W3, b3, out);
}

// Round 5
// 472.932 us; speedup vs baseline: 1.5765x; 1.0425x over previous
//
#include <hip/hip_runtime.h>
#include <hip/hip_bf16.h>

#define N_NODES 32768
#define E_EDGES 1048576
#define HID 128
#define G_GRAPHS 128
#define NPG 256
#define NH 8
#define DH 16
#define EPS 1e-5f
#define CHUNK 4096
#define BCAP 8192

typedef __attribute__((ext_vector_type(4))) float f32x4;
typedef __attribute__((ext_vector_type(4))) short bf16x4;

static __device__ __forceinline__ unsigned short bfbits(float f) {
    return __builtin_bit_cast(unsigned short, __float2bfloat16(f));
}
static __device__ __forceinline__ float bf2f(unsigned short u) {
    return __builtin_bit_cast(float, (unsigned)u << 16);
}

// ---------------- helpers ----------------
__device__ __forceinline__ void ln_stats128(float v, float& mean, float& istd, float* red) {
    float s = v, s2 = v * v;
#pragma unroll
    for (int off = 32; off; off >>= 1) { s += __shfl_xor(s, off); s2 += __shfl_xor(s2, off); }
    int w = threadIdx.x >> 6;
    if ((threadIdx.x & 63) == 0) { red[w * 2] = s; red[w * 2 + 1] = s2; }
    __syncthreads();
    float ts = red[0] + red[2], ts2 = red[1] + red[3];
    mean = ts * (1.f / 128.f);
    float var = ts2 * (1.f / 128.f) - mean * mean;
    istd = rsqrtf(var + EPS);
    __syncthreads();
}

// ---------------- CSR build: bucketed counting sort ----------------
__global__ __launch_bounds__(256) void bucket_count(const int* __restrict__ dst,
                                                    int* __restrict__ bucket_cnt) {
    __shared__ int bcnt[256];
    int tid = threadIdx.x;
    bcnt[tid] = 0;
    __syncthreads();
    int base = blockIdx.x * CHUNK;
#pragma unroll
    for (int j = 0; j < 16; j++) {
        int d = dst[base + j * 256 + tid];
        atomicAdd(&bcnt[d >> 7], 1);
    }
    __syncthreads();
    atomicAdd(&bucket_cnt[tid], bcnt[tid]);
}

__global__ __launch_bounds__(256) void scan_buckets(const int* __restrict__ bucket_cnt,
                                                    int* __restrict__ bucket_base,
                                                    int* __restrict__ bucket_fill) {
    __shared__ int sc[256];
    int t = threadIdx.x;
    int c = bucket_cnt[t];
    sc[t] = c;
    __syncthreads();
    for (int off = 1; off < 256; off <<= 1) {
        int v = (t >= off) ? sc[t - off] : 0;
        __syncthreads();
        sc[t] += v;
        __syncthreads();
    }
    int ex = sc[t] - c;
    bucket_base[t] = ex;
    bucket_fill[t] = ex;
    if (t == 255) bucket_base[256] = sc[255];
}

__global__ __launch_bounds__(256) void bucket_scatter(const int* __restrict__ src,
                                                      const int* __restrict__ dst,
                                                      int* __restrict__ bucket_fill,
                                                      int* __restrict__ packed) {
    __shared__ int bcnt[256];
    __shared__ int lsc[256];
    __shared__ int delta[256];
    __shared__ int sorted[CHUNK];
    int tid = threadIdx.x;
    int base = blockIdx.x * CHUNK;
    int pk[16], bk[16], rk[16];
    bcnt[tid] = 0;
    __syncthreads();
#pragma unroll
    for (int j = 0; j < 16; j++) {
        int e = base + j * 256 + tid;
        int d = dst[e], s = src[e];
        pk[j] = (d << 15) | s;
        bk[j] = d >> 7;
    }
#pragma unroll
    for (int j = 0; j < 16; j++) rk[j] = atomicAdd(&bcnt[bk[j]], 1);
    __syncthreads();
    int cnt_t = bcnt[tid];
    lsc[tid] = cnt_t;
    __syncthreads();
    for (int off = 1; off < 256; off <<= 1) {
        int v = (tid >= off) ? lsc[tid - off] : 0;
        __syncthreads();
        lsc[tid] += v;
        __syncthreads();
    }
    int ls_t = lsc[tid] - cnt_t;
    __syncthreads();
    lsc[tid] = ls_t;
    int g = 0;
    if (cnt_t > 0) g = atomicAdd(&bucket_fill[tid], cnt_t);
    delta[tid] = g - ls_t;
    __syncthreads();
#pragma unroll
    for (int j = 0; j < 16; j++) sorted[lsc[bk[j]] + rk[j]] = pk[j];
    __syncthreads();
    for (int i = tid; i < CHUNK; i += 256) {
        int u = sorted[i];
        int b2 = u >> 22;
        packed[delta[b2] + i] = u;
    }
}

__global__ __launch_bounds__(256) void csr_build(const int* __restrict__ bucket_base,
                                                 const int* __restrict__ packed,
                                                 int* __restrict__ srcs,
                                                 int* __restrict__ row_ptr,
                                                 float* __restrict__ dis) {
    __shared__ int ncnt[128];
    __shared__ int sc[128];
    __shared__ int fill[128];
    __shared__ int outl[BCAP];
    int b = blockIdx.x, tid = threadIdx.x;
    int c0 = bucket_base[b], c1 = bucket_base[b + 1];
    int cnt = c1 - c0;
    if (tid < 128) ncnt[tid] = 0;
    __syncthreads();
    for (int i = tid; i < cnt; i += 256) {
        int u = packed[c0 + i];
        atomicAdd(&ncnt[(u >> 15) & 127], 1);
    }
    __syncthreads();
    int c = (tid < 128) ? ncnt[tid] : 0;
    if (tid < 128) sc[tid] = c;
    __syncthreads();
    for (int off = 1; off < 128; off <<= 1) {
        int v = (tid < 128 && tid >= off) ? sc[tid - off] : 0;
        __syncthreads();
        if (tid < 128) sc[tid] += v;
        __syncthreads();
    }
    if (tid < 128) {
        int ex = sc[tid] - c;
        fill[tid] = ex;
        int node = b * 128 + tid;
        row_ptr[node] = c0 + ex;
        dis[node] = rsqrtf((float)(c + 1));
    }
    if (b == 255 && tid == 0) row_ptr[N_NODES] = c1;
    __syncthreads();
    if (cnt <= BCAP) {
        for (int i = tid; i < cnt; i += 256) {
            int u = packed[c0 + i];
            int p = atomicAdd(&fill[(u >> 15) & 127], 1);
            outl[p] = u & 32767;
        }
        __syncthreads();
        for (int i = tid; i < cnt; i += 256) srcs[c0 + i] = outl[i];
    } else {
        for (int i = tid; i < cnt; i += 256) {
            int u = packed[c0 + i];
            int p = atomicAdd(&fill[(u >> 15) & 127], 1);
            srcs[c0 + p] = u & 32767;
        }
    }
}

// ---------------- weight prep: pack all 128x128 weights into bf16 MFMA B-fragment order
// Wpk layout per matrix: idx = ((jt*8+kt)*64 + lane)*4 + j  holds  B[k][col],
// k = kt*16+(lane>>4)*4+j, col = jt*16+(lane&15).
// m 0..2: Wc[m] (B=W).  m 3..6: Wq,Wk,Wv,Wo (B=W^T, i.e. W[col][k]).
__global__ __launch_bounds__(256) void prep_weights(const float* __restrict__ Wc,
                                                    const float* __restrict__ Wq,
                                                    const float* __restrict__ Wk,
                                                    const float* __restrict__ Wv,
                                                    const float* __restrict__ Wo,
                                                    const float* __restrict__ bq,
                                                    const float* __restrict__ bk,
                                                    const float* __restrict__ bv,
                                                    unsigned short* __restrict__ Wpk,
                                                    float* __restrict__ bT) {
    int m = blockIdx.y;
    int idx = blockIdx.x * 256 + threadIdx.x;   // 0..16383
    int j = idx & 3, ln = (idx >> 2) & 63, kt = (idx >> 8) & 7, jt = (idx >> 11) & 7;
    int k = kt * 16 + (ln >> 4) * 4 + j;
    int col = jt * 16 + (ln & 15);
    float val;
    if (m < 3) val = Wc[m * 16384 + k * 128 + col];
    else {
        const float* W = (m == 3) ? Wq : (m == 4) ? Wk : (m == 5) ? Wv : Wo;
        val = W[col * 128 + k];
    }
    Wpk[m * 16384 + idx] = bfbits(val);
    if (m >= 3 && m < 6 && idx < 128) {
        const float* bs = (m == 3) ? bq : (m == 4) ? bk : bv;
        bT[(m - 3) * 128 + idx] = bs[idx];
    }
}

// ---------------- input projection + LN + ReLU -> bf16 ----------------
__global__ __launch_bounds__(128) void input_proj(const float* __restrict__ x,
                                                  const float* __restrict__ W,
                                                  const float* __restrict__ b,
                                                  const float* __restrict__ g,
                                                  const float* __restrict__ be,
                                                  unsigned short* __restrict__ h16) {
    int n = blockIdx.x, j = threadIdx.x;
    __shared__ float xs[15];
    __shared__ float red[4];
    if (j < 15) xs[j] = x[n * 15 + j];
    __syncthreads();
    float acc = b[j];
#pragma unroll
    for (int k = 0; k < 15; k++) acc += xs[k] * W[k * 128 + j];
    float m, is;
    ln_stats128(acc, m, is, red);
    float y = (acc - m) * is * g[j] + be[j];
    h16[(long)n * 128 + j] = bfbits(fmaxf(y, 0.f));
}

// ---------------- MFMA GEMM: out[N][128] = in[N][128] @ B  (bf16 in, bf16 out) ----------------
// MODE 0: plain.  MODE 1: +bias.  MODE 2: +bias +resid(bf16), then LN(gamma,beta).
// Fragment layout validated by the attention kernel (mfma_f32_16x16x16bf16_1k):
//   A: row=lane&15, k=(lane>>4)*4+j ; B: col=lane&15, k=(lane>>4)*4+j ; D: col=lane&15, row=(lane>>4)*4+r
template <int MODE>
__device__ __forceinline__ void gemm_mfma_body(const unsigned short* __restrict__ in16,
                                               const unsigned short* __restrict__ Wpk,
                                               const float* __restrict__ bias,
                                               const unsigned short* __restrict__ resid16,
                                               const float* __restrict__ gamma,
                                               const float* __restrict__ beta,
                                               unsigned short* __restrict__ out16) {
    __shared__ unsigned short Ws[16384];     // 32KB packed B-fragments
    __shared__ unsigned short Hs[64][136];   // padded: 272B rows (16B-aligned, 2-way banks)
    int tid = threadIdx.x;
    long base = (long)blockIdx.x * 64;
    {
        const uint4* s4 = (const uint4*)Wpk;
        uint4* d4 = (uint4*)Ws;
        for (int i = tid; i < 2048; i += 256) d4[i] = s4[i];
        const unsigned short* hsrc = in16 + base * 128;
        for (int i = tid; i < 1024; i += 256) {
            int r = i >> 4, c8 = i & 15;
            *(uint4*)&Hs[r][c8 * 8] = *(const uint4*)&hsrc[r * 128 + c8 * 8];
        }
    }
    __syncthreads();
    int wv = tid >> 6, lane = tid & 63;
    int ql = lane & 15, qg = lane >> 4;
    f32x4 acc[8];
#pragma unroll
    for (int jt = 0; jt < 8; jt++) acc[jt] = (f32x4){0.f, 0.f, 0.f, 0.f};
#pragma unroll
    for (int kt = 0; kt < 8; kt++) {
        bf16x4 af = *(const bf16x4*)&Hs[wv * 16 + ql][kt * 16 + qg * 4];
#pragma unroll
        for (int jt = 0; jt < 8; jt++) {
            bf16x4 bf = *(const bf16x4*)&Ws[((jt * 8 + kt) * 64 + lane) * 4];
            acc[jt] = __builtin_amdgcn_mfma_f32_16x16x16bf16_1k(af, bf, acc[jt], 0, 0, 0);
        }
    }
    if (MODE >= 1) {
#pragma unroll
        for (int jt = 0; jt < 8; jt++) {
            float bv = bias[jt * 16 + ql];
#pragma unroll
            for (int r = 0; r < 4; r++) acc[jt][r] += bv;
        }
    }
    if (MODE == 2) {
#pragma unroll
        for (int jt = 0; jt < 8; jt++)
#pragma unroll
            for (int r = 0; r < 4; r++)
                acc[jt][r] += bf2f(resid16[(base + wv * 16 + qg * 4 + r) * 128 + jt * 16 + ql]);
        float s[4], s2[4], mean[4], istd[4];
#pragma unroll
        for (int r = 0; r < 4; r++) { s[r] = 0.f; s2[r] = 0.f; }
#pragma unroll
        for (int jt = 0; jt < 8; jt++)
#pragma unroll
            for (int r = 0; r < 4; r++) { float v = acc[jt][r]; s[r] += v; s2[r] += v * v; }
#pragma unroll
        for (int off = 1; off < 16; off <<= 1)
#pragma unroll
            for (int r = 0; r < 4; r++) {
                s[r] += __shfl_xor(s[r], off);
                s2[r] += __shfl_xor(s2[r], off);
            }
#pragma unroll
        for (int r = 0; r < 4; r++) {
            mean[r] = s[r] * (1.f / 128.f);
            float var = s2[r] * (1.f / 128.f) - mean[r] * mean[r];
            istd[r] = rsqrtf(var + EPS);
        }
#pragma unroll
        for (int jt = 0; jt < 8; jt++) {
            float gv = gamma[jt * 16 + ql], bev = beta[jt * 16 + ql];
#pragma unroll
            for (int r = 0; r < 4; r++)
                acc[jt][r] = (acc[jt][r] - mean[r]) * istd[r] * gv + bev;
        }
    }
    // store via LDS transpose: wave w only touches its own 16 rows of Hs (it alone read them)
#pragma unroll
    for (int jt = 0; jt < 8; jt++)
#pragma unroll
        for (int r = 0; r < 4; r++)
            Hs[wv * 16 + qg * 4 + r][jt * 16 + ql] = bfbits(acc[jt][r]);
#pragma unroll
    for (int p = 0; p < 4; p++) {
        int rl = p * 4 + qg;
        uint4 v = *(const uint4*)&Hs[wv * 16 + rl][ql * 8];
        *(uint4*)&out16[(base + wv * 16 + rl) * 128 + ql * 8] = v;
    }
}

template <int MODE>
__global__ __launch_bounds__(256) void gemm_mfma(const unsigned short* __restrict__ in16,
                                                 const unsigned short* __restrict__ Wpk,
                                                 const float* __restrict__ bias,
                                                 const unsigned short* __restrict__ resid16,
                                                 const float* __restrict__ gamma,
                                                 const float* __restrict__ beta,
                                                 unsigned short* __restrict__ out16) {
    gemm_mfma_body<MODE>(in16, Wpk, bias, resid16, gamma, beta, out16);
}

__global__ __launch_bounds__(256) void gemm_qkv(const unsigned short* __restrict__ in16,
                                                const unsigned short* __restrict__ Wpk,
                                                const float* __restrict__ bT,
                                                unsigned short* __restrict__ outb) {
    int y = blockIdx.y;
    gemm_mfma_body<1>(in16, Wpk + (3 + y) * 16384, bT + y * 128, nullptr, nullptr, nullptr,
                      outb + (long)y * N_NODES * 128);
}

// ---------------- GCN aggregation v3: wave-per-node, readlane broadcast, barrier-free ----------
__global__ __launch_bounds__(256) void gcn_agg(const unsigned short* __restrict__ hW,
                                               const int* __restrict__ row_ptr,
                                               const int* __restrict__ srcs,
                                               const float* __restrict__ dis,
                                               const float* __restrict__ bias,
                                               const float* __restrict__ gamma,
                                               const float* __restrict__ beta,
                                               unsigned short* __restrict__ h16, int with_resid) {
    int wv = threadIdx.x >> 6, lane = threadIdx.x & 63;
    int n = blockIdx.x * 4 + wv;
    int r0 = row_ptr[n], r1 = row_ptr[n + 1];
    float dn = dis[n];
    unsigned su = *(const unsigned*)&hW[(long)n * 128 + lane * 2];
    float dnn = dn * dn;
    float a0 = bf2f((unsigned short)(su & 0xffff)) * dnn;
    float a1 = bf2f((unsigned short)(su >> 16)) * dnn;
    for (int b = r0; b < r1; b += 64) {
        int cnt = min(64, r1 - b);
        int sv = 0;
        float cv = 0.f;
        if (lane < cnt) {
            sv = srcs[b + lane];
            cv = dis[sv] * dn;
        }
#pragma unroll 4
        for (int j = 0; j < cnt; ++j) {
            int s = __builtin_amdgcn_readlane(sv, j);
            float c = __builtin_bit_cast(float,
                        __builtin_amdgcn_readlane(__builtin_bit_cast(int, cv), j));
            unsigned u = *(const unsigned*)&hW[(long)s * 128 + lane * 2];
            a0 += bf2f((unsigned short)(u & 0xffff)) * c;
            a1 += bf2f((unsigned short)(u >> 16)) * c;
        }
    }
    float2 bb = *(const float2*)&bias[lane * 2];
    a0 += bb.x;
    a1 += bb.y;
    float s = a0 + a1, s2 = a0 * a0 + a1 * a1;
#pragma unroll
    for (int off = 1; off < 64; off <<= 1) { s += __shfl_xor(s, off); s2 += __shfl_xor(s2, off); }
    float mean = s * (1.f / 128.f);
    float var = s2 * (1.f / 128.f) - mean * mean;
    float is = rsqrtf(var + EPS);
    float2 gg = *(const float2*)&gamma[lane * 2];
    float2 be2 = *(const float2*)&beta[lane * 2];
    float y0 = fmaxf((a0 - mean) * is * gg.x + be2.x, 0.f);
    float y1 = fmaxf((a1 - mean) * is * gg.y + be2.y, 0.f);
    if (with_resid) {
        unsigned ru = *(const unsigned*)&h16[(long)n * 128 + lane * 2];
        y0 += bf2f((unsigned short)(ru & 0xffff));
        y1 += bf2f((unsigned short)(ru >> 16));
    }
    unsigned outu = (unsigned)bfbits(y0) | ((unsigned)bfbits(y1) << 16);
    *(unsigned*)&h16[(long)n * 128 + lane * 2] = outu;
}

// ---------------- attention: MFMA (swapped QK^T), bf16 output ----------------
__global__ __launch_bounds__(256) void attention(const unsigned short* __restrict__ q16,
                                                 const unsigned short* __restrict__ k16,
                                                 const unsigned short* __restrict__ v16,
                                                 unsigned short* __restrict__ o16) {
    int g = blockIdx.x, hh = blockIdx.y;
    int tid = threadIdx.x;
    long gbase = ((long)g * NPG) * 128 + hh * 16;
    __shared__ unsigned short Ksh[256][24];
    __shared__ unsigned short Qsh[256][24];
    __shared__ unsigned short Vt[16][264];
    {
        const unsigned short* kp = k16 + gbase + (long)tid * 128;
        uint4 a = *(const uint4*)kp, b = *(const uint4*)(kp + 8);
        *(uint4*)&Ksh[tid][0] = a; *(uint4*)&Ksh[tid][8] = b;
        const unsigned short* qp = q16 + gbase + (long)tid * 128;
        uint4 c = *(const uint4*)qp, d = *(const uint4*)(qp + 8);
        *(uint4*)&Qsh[tid][0] = c; *(uint4*)&Qsh[tid][8] = d;
        const unsigned short* vp = v16 + gbase + (long)tid * 128;
#pragma unroll
        for (int dd = 0; dd < 16; dd++) Vt[dd][tid] = vp[dd];
    }
    __syncthreads();
    int wv = tid >> 6, lane = tid & 63;
    int qg = lane >> 4, ql = lane & 15;
    bf16x4 vfrag[16];
#pragma unroll
    for (int kt = 0; kt < 16; kt++)
        vfrag[kt] = *(const bf16x4*)&Vt[ql][kt * 16 + qg * 4];
    const float C = 0.36067376022224085f;   // 0.25 * log2(e)
    for (int qi = 0; qi < 4; qi++) {
        int qt = wv * 4 + qi;
        bf16x4 qfrag = *(const bf16x4*)&Qsh[qt * 16 + ql][qg * 4];
        float lsum = 0.f;
        bf16x4 pb[16];
        f32x4 z4 = {0.f, 0.f, 0.f, 0.f};
#pragma unroll
        for (int kt = 0; kt < 16; kt++) {
            bf16x4 kfrag = *(const bf16x4*)&Ksh[kt * 16 + ql][qg * 4];
            f32x4 s4 = __builtin_amdgcn_mfma_f32_16x16x16bf16_1k(kfrag, qfrag, z4, 0, 0, 0);
            bf16x4 pbk;
#pragma unroll
            for (int r = 0; r < 4; r++) {
                float pv = exp2f(s4[r] * C);
                lsum += pv;
                pbk[r] = (short)bfbits(pv);
            }
            pb[kt] = pbk;
        }
        f32x4 oacc = {0.f, 0.f, 0.f, 0.f};
#pragma unroll
        for (int kt = 0; kt < 16; kt++)
            oacc = __builtin_amdgcn_mfma_f32_16x16x16bf16_1k(vfrag[kt], pb[kt], oacc, 0, 0, 0);
        lsum += __shfl_xor(lsum, 16);
        lsum += __shfl_xor(lsum, 32);
        float inv = 1.f / lsum;
        unsigned short* op = o16 + gbase + (long)(qt * 16 + ql) * 128 + 4 * qg;
        ushort4 st;
        st.x = bfbits(oacc[0] * inv);
        st.y = bfbits(oacc[1] * inv);
        st.z = bfbits(oacc[2] * inv);
        st.w = bfbits(oacc[3] * inv);
        *(ushort4*)op = st;
    }
}

// ---------------- pooling: mean/max/sum per graph (bf16 in) ----------------
__global__ __launch_bounds__(256) void pool_kernel(const unsigned short* __restrict__ hg,
                                                   float* __restrict__ pooled) {
    int g = blockIdx.x;
    int lane = threadIdx.x & 63, grp = threadIdx.x >> 6;
    __shared__ float ssum[4][128];
    __shared__ float smax[4][128];
    float s0 = 0.f, s1 = 0.f, m0 = -1e30f, m1 = -1e30f;
    for (int i = grp * 64; i < grp * 64 + 64; i++) {
        unsigned u = *(const unsigned*)&hg[((long)g * NPG + i) * 128 + lane * 2];
        float v0 = bf2f((unsigned short)(u & 0xffff));
        float v1 = bf2f((unsigned short)(u >> 16));
        s0 += v0; s1 += v1;
        m0 = fmaxf(m0, v0); m1 = fmaxf(m1, v1);
    }
    ssum[grp][lane * 2] = s0; ssum[grp][lane * 2 + 1] = s1;
    smax[grp][lane * 2] = m0; smax[grp][lane * 2 + 1] = m1;
    __syncthreads();
    if (grp == 0) {
        for (int jj = lane; jj < 128; jj += 64) {
            float ts = ssum[0][jj] + ssum[1][jj] + ssum[2][jj] + ssum[3][jj];
            float tm = fmaxf(fmaxf(smax[0][jj], smax[1][jj]), fmaxf(smax[2][jj], smax[3][jj]));
            pooled[g * 384 + jj] = ts * (1.f / 256.f);
            pooled[g * 384 + 128 + jj] = tm;
            pooled[g * 384 + 256 + jj] = ts;
        }
    }
}

// ---------------- classifier ----------------
__global__ __launch_bounds__(128) void classifier(const float* __restrict__ pooled,
                                                  const float* __restrict__ W1, const float* __restrict__ b1,
                                                  const float* __restrict__ g1, const float* __restrict__ be1,
                                                  const float* __restrict__ W2, const float* __restrict__ b2,
                                                  const float* __restrict__ W3, const float* __restrict__ b3,
                                                  float* __restrict__ out) {
    int g = blockIdx.x, j = threadIdx.x;
    __shared__ float pl[384];
    __shared__ float z1s[128];
    __shared__ float z2s[64];
    __shared__ float red[4];
    for (int i = j; i < 384; i += 128) pl[i] = pooled[g * 384 + i];
    __syncthreads();
    float acc = b1[j];
    for (int kk = 0; kk < 384; kk++) acc += pl[kk] * W1[kk * 128 + j];
    float m, is;
    ln_stats128(acc, m, is, red);
    float y = fmaxf((acc - m) * is * g1[j] + be1[j], 0.f);
    z1s[j] = y;
    __syncthreads();
    if (j < 64) {
        float a2 = b2[j];
        for (int kk = 0; kk < 128; kk++) a2 += z1s[kk] * W2[kk * 64 + j];
        z2s[j] = fmaxf(a2, 0.f);
    }
    __syncthreads();
    if (j < 64) {
        float vv = z2s[j];
        float p0 = vv * W3[j * 2];
        float p1 = vv * W3[j * 2 + 1];
#pragma unroll
        for (int off = 32; off; off >>= 1) { p0 += __shfl_xor(p0, off); p1 += __shfl_xor(p1, off); }
        if (j == 0) {
            out[g * 2] = p0 + b3[0];
            out[g * 2 + 1] = p1 + b3[1];
        }
    }
}

// ---------------- launch ----------------
extern "C" void kernel_launch(void* const* d_in, const int* in_sizes, int n_in,
                              void* d_out, int out_size, void* d_ws, size_t ws_size,
                              hipStream_t stream) {
    const float* x = (const float*)d_in[0];
    const int* ei = (const int*)d_in[1];
    const float* W_in = (const float*)d_in[3];
    const float* b_in = (const float*)d_in[4];
    const float* g_in = (const float*)d_in[5];
    const float* be_in = (const float*)d_in[6];
    const float* Wc = (const float*)d_in[7];
    const float* bc = (const float*)d_in[8];
    const float* gn = (const float*)d_in[9];
    const float* bn = (const float*)d_in[10];
    const float* Wq = (const float*)d_in[11];
    const float* bq = (const float*)d_in[12];
    const float* Wk = (const float*)d_in[13];
    const float* bk = (const float*)d_in[14];
    const float* Wv = (const float*)d_in[15];
    const float* bv = (const float*)d_in[16];
    const float* Wo = (const float*)d_in[17];
    const float* bo = (const float*)d_in[18];
    const float* ga = (const float*)d_in[19];
    const float* ba = (const float*)d_in[20];
    const float* W1 = (const float*)d_in[21];
    const float* b1 = (const float*)d_in[22];
    const float* g1 = (const float*)d_in[23];
    const float* be1 = (const float*)d_in[24];
    const float* W2 = (const float*)d_in[25];
    const float* b2 = (const float*)d_in[26];
    const float* W3 = (const float*)d_in[27];
    const float* b3 = (const float*)d_in[28];
    float* out = (float*)d_out;

    const long NF = (long)N_NODES * 128;
    unsigned char* wsb = (unsigned char*)d_ws;
    const size_t MB = 1 << 20;
    unsigned short* h16 = (unsigned short*)(wsb);             // 8MB
    unsigned short* hw16 = (unsigned short*)(wsb + 8 * MB);   // 8MB
    unsigned short* qkv16 = (unsigned short*)(wsb + 16 * MB); // 24MB
    unsigned short* o16 = (unsigned short*)(wsb + 40 * MB);   // 8MB
    unsigned short* hg16 = (unsigned short*)(wsb + 48 * MB);  // 8MB
    unsigned short* Wpk = (unsigned short*)(wsb + 56 * MB);   // 224KB
    int* packed = (int*)(wsb + 57 * MB);                      // 4MB
    int* srcs = (int*)(wsb + 61 * MB);                        // 4MB
    int* row_ptr = (int*)(wsb + 65 * MB);                     // 128KB+4
    float* dis = (float*)(wsb + 66 * MB);                     // 128KB
    float* bT = (float*)(wsb + 67 * MB);                      // 1.5KB
    float* pooled = (float*)(wsb + 67 * MB + 4096);           // 192KB
    int* bucket_cnt = (int*)(wsb + 68 * MB);                  // 256
    int* bucket_base = bucket_cnt + 256;                      // 257
    int* bucket_fill = bucket_base + 257;                     // 256

    const int* e_src = ei;
    const int* e_dst = ei + E_EDGES;

    hipMemsetAsync(bucket_cnt, 0, 256 * sizeof(int), stream);
    prep_weights<<<dim3(64, 7), 256, 0, stream>>>(Wc, Wq, Wk, Wv, Wo, bq, bk, bv, Wpk, bT);
    bucket_count<<<E_EDGES / CHUNK, 256, 0, stream>>>(e_dst, bucket_cnt);
    scan_buckets<<<1, 256, 0, stream>>>(bucket_cnt, bucket_base, bucket_fill);
    bucket_scatter<<<E_EDGES / CHUNK, 256, 0, stream>>>(e_src, e_dst, bucket_fill, packed);
    csr_build<<<256, 256, 0, stream>>>(bucket_base, packed, srcs, row_ptr, dis);

    input_proj<<<N_NODES, 128, 0, stream>>>(x, W_in, b_in, g_in, be_in, h16);

    for (int i = 0; i < 3; i++) {
        gemm_mfma<0><<<N_NODES / 64, 256, 0, stream>>>(h16, Wpk + i * 16384, nullptr, nullptr,
                                                       nullptr, nullptr, hw16);
        gcn_agg<<<N_NODES / 4, 256, 0, stream>>>(hw16, row_ptr, srcs, dis, bc + i * 128,
                                                 gn + i * 128, bn + i * 128, h16, i > 0);
    }

    gemm_qkv<<<dim3(N_NODES / 64, 3), 256, 0, stream>>>(h16, Wpk, bT, qkv16);

    attention<<<dim3(G_GRAPHS, NH), 256, 0, stream>>>(qkv16, qkv16 + NF, qkv16 + 2 * NF, o16);

    gemm_mfma<2><<<N_NODES / 64, 256, 0, stream>>>(o16, Wpk + 6 * 16384, bo, h16, ga, ba, hg16);

    pool_kernel<<<G_GRAPHS, 256, 0, stream>>>(hg16, pooled);
    classifier<<<G_GRAPHS, 128, 0, stream>>>(pooled, W1, b1, g1, be1, W2, b2, W3, b3, out);
}

// Round 6
// 365.189 us; speedup vs baseline: 2.0416x; 1.2950x over previous
//
#include <hip/hip_runtime.h>
#include <hip/hip_bf16.h>

#define N_NODES 32768
#define E_EDGES 1048576
#define HID 128
#define G_GRAPHS 128
#define NPG 256
#define NH 8
#define DH 16
#define EPS 1e-5f
#define CHUNK 4096
#define BCAP 8192

typedef __attribute__((ext_vector_type(4))) float f32x4;
typedef __attribute__((ext_vector_type(4))) short bf16x4;

static __device__ __forceinline__ unsigned short bfbits(float f) {
    return __builtin_bit_cast(unsigned short, __float2bfloat16(f));
}
static __device__ __forceinline__ float bf2f(unsigned short u) {
    return __builtin_bit_cast(float, (unsigned)u << 16);
}

// ---------------- helpers ----------------
__device__ __forceinline__ void ln_stats128(float v, float& mean, float& istd, float* red) {
    float s = v, s2 = v * v;
#pragma unroll
    for (int off = 32; off; off >>= 1) { s += __shfl_xor(s, off); s2 += __shfl_xor(s2, off); }
    int w = threadIdx.x >> 6;
    if ((threadIdx.x & 63) == 0) { red[w * 2] = s; red[w * 2 + 1] = s2; }
    __syncthreads();
    float ts = red[0] + red[2], ts2 = red[1] + red[3];
    mean = ts * (1.f / 128.f);
    float var = ts2 * (1.f / 128.f) - mean * mean;
    istd = rsqrtf(var + EPS);
    __syncthreads();
}

// ---------------- CSR build: bucketed counting sort ----------------
__global__ __launch_bounds__(256) void bucket_count(const int* __restrict__ dst,
                                                    int* __restrict__ bucket_cnt) {
    __shared__ int bcnt[256];
    int tid = threadIdx.x;
    bcnt[tid] = 0;
    __syncthreads();
    int base = blockIdx.x * CHUNK;
#pragma unroll
    for (int j = 0; j < 16; j++) {
        int d = dst[base + j * 256 + tid];
        atomicAdd(&bcnt[d >> 7], 1);
    }
    __syncthreads();
    atomicAdd(&bucket_cnt[tid], bcnt[tid]);
}

__global__ __launch_bounds__(256) void scan_buckets(const int* __restrict__ bucket_cnt,
                                                    int* __restrict__ bucket_base,
                                                    int* __restrict__ bucket_fill) {
    __shared__ int sc[256];
    int t = threadIdx.x;
    int c = bucket_cnt[t];
    sc[t] = c;
    __syncthreads();
    for (int off = 1; off < 256; off <<= 1) {
        int v = (t >= off) ? sc[t - off] : 0;
        __syncthreads();
        sc[t] += v;
        __syncthreads();
    }
    int ex = sc[t] - c;
    bucket_base[t] = ex;
    bucket_fill[t] = ex;
    if (t == 255) bucket_base[256] = sc[255];
}

__global__ __launch_bounds__(256) void bucket_scatter(const int* __restrict__ src,
                                                      const int* __restrict__ dst,
                                                      int* __restrict__ bucket_fill,
                                                      int* __restrict__ packed) {
    __shared__ int bcnt[256];
    __shared__ int lsc[256];
    __shared__ int delta[256];
    __shared__ int sorted[CHUNK];
    int tid = threadIdx.x;
    int base = blockIdx.x * CHUNK;
    int pk[16], bk[16], rk[16];
    bcnt[tid] = 0;
    __syncthreads();
#pragma unroll
    for (int j = 0; j < 16; j++) {
        int e = base + j * 256 + tid;
        int d = dst[e], s = src[e];
        pk[j] = (d << 15) | s;
        bk[j] = d >> 7;
    }
#pragma unroll
    for (int j = 0; j < 16; j++) rk[j] = atomicAdd(&bcnt[bk[j]], 1);
    __syncthreads();
    int cnt_t = bcnt[tid];
    lsc[tid] = cnt_t;
    __syncthreads();
    for (int off = 1; off < 256; off <<= 1) {
        int v = (tid >= off) ? lsc[tid - off] : 0;
        __syncthreads();
        lsc[tid] += v;
        __syncthreads();
    }
    int ls_t = lsc[tid] - cnt_t;
    __syncthreads();
    lsc[tid] = ls_t;
    int g = 0;
    if (cnt_t > 0) g = atomicAdd(&bucket_fill[tid], cnt_t);
    delta[tid] = g - ls_t;
    __syncthreads();
#pragma unroll
    for (int j = 0; j < 16; j++) sorted[lsc[bk[j]] + rk[j]] = pk[j];
    __syncthreads();
    for (int i = tid; i < CHUNK; i += 256) {
        int u = sorted[i];
        int b2 = u >> 22;
        packed[delta[b2] + i] = u;
    }
}

__global__ __launch_bounds__(256) void csr_build(const int* __restrict__ bucket_base,
                                                 const int* __restrict__ packed,
                                                 int* __restrict__ srcs,
                                                 int* __restrict__ row_ptr,
                                                 float* __restrict__ dis) {
    __shared__ int ncnt[128];
    __shared__ int sc[128];
    __shared__ int fill[128];
    __shared__ int outl[BCAP];
    int b = blockIdx.x, tid = threadIdx.x;
    int c0 = bucket_base[b], c1 = bucket_base[b + 1];
    int cnt = c1 - c0;
    if (tid < 128) ncnt[tid] = 0;
    __syncthreads();
    for (int i = tid; i < cnt; i += 256) {
        int u = packed[c0 + i];
        atomicAdd(&ncnt[(u >> 15) & 127], 1);
    }
    __syncthreads();
    int c = (tid < 128) ? ncnt[tid] : 0;
    if (tid < 128) sc[tid] = c;
    __syncthreads();
    for (int off = 1; off < 128; off <<= 1) {
        int v = (tid < 128 && tid >= off) ? sc[tid - off] : 0;
        __syncthreads();
        if (tid < 128) sc[tid] += v;
        __syncthreads();
    }
    if (tid < 128) {
        int ex = sc[tid] - c;
        fill[tid] = ex;
        int node = b * 128 + tid;
        row_ptr[node] = c0 + ex;
        dis[node] = rsqrtf((float)(c + 1));
    }
    if (b == 255 && tid == 0) row_ptr[N_NODES] = c1;
    __syncthreads();
    if (cnt <= BCAP) {
        for (int i = tid; i < cnt; i += 256) {
            int u = packed[c0 + i];
            int p = atomicAdd(&fill[(u >> 15) & 127], 1);
            outl[p] = u & 32767;
        }
        __syncthreads();
        for (int i = tid; i < cnt; i += 256) srcs[c0 + i] = outl[i];
    } else {
        for (int i = tid; i < cnt; i += 256) {
            int u = packed[c0 + i];
            int p = atomicAdd(&fill[(u >> 15) & 127], 1);
            srcs[c0 + p] = u & 32767;
        }
    }
}

// ---------------- weight prep ----------------
__global__ __launch_bounds__(256) void prep_weights(const float* __restrict__ Wc,
                                                    const float* __restrict__ Wq,
                                                    const float* __restrict__ Wk,
                                                    const float* __restrict__ Wv,
                                                    const float* __restrict__ Wo,
                                                    const float* __restrict__ bq,
                                                    const float* __restrict__ bk,
                                                    const float* __restrict__ bv,
                                                    unsigned short* __restrict__ Wpk,
                                                    float* __restrict__ bT) {
    int m = blockIdx.y;
    int idx = blockIdx.x * 256 + threadIdx.x;   // 0..16383
    int j = idx & 3, ln = (idx >> 2) & 63, kt = (idx >> 8) & 7, jt = (idx >> 11) & 7;
    int k = kt * 16 + (ln >> 4) * 4 + j;
    int col = jt * 16 + (ln & 15);
    float val;
    if (m < 3) val = Wc[m * 16384 + k * 128 + col];
    else {
        const float* W = (m == 3) ? Wq : (m == 4) ? Wk : (m == 5) ? Wv : Wo;
        val = W[col * 128 + k];
    }
    Wpk[m * 16384 + idx] = bfbits(val);
    if (m >= 3 && m < 6 && idx < 128) {
        const float* bs = (m == 3) ? bq : (m == 4) ? bk : bv;
        bT[(m - 3) * 128 + idx] = bs[idx];
    }
}

// ---------------- input projection + LN + ReLU -> bf16 ----------------
__global__ __launch_bounds__(128) void input_proj(const float* __restrict__ x,
                                                  const float* __restrict__ W,
                                                  const float* __restrict__ b,
                                                  const float* __restrict__ g,
                                                  const float* __restrict__ be,
                                                  unsigned short* __restrict__ h16) {
    int n = blockIdx.x, j = threadIdx.x;
    __shared__ float xs[15];
    __shared__ float red[4];
    if (j < 15) xs[j] = x[n * 15 + j];
    __syncthreads();
    float acc = b[j];
#pragma unroll
    for (int k = 0; k < 15; k++) acc += xs[k] * W[k * 128 + j];
    float m, is;
    ln_stats128(acc, m, is, red);
    float y = (acc - m) * is * g[j] + be[j];
    h16[(long)n * 128 + j] = bfbits(fmaxf(y, 0.f));
}

// ---------------- MFMA GEMM ----------------
template <int MODE>
__device__ __forceinline__ void gemm_mfma_body(const unsigned short* __restrict__ in16,
                                               const unsigned short* __restrict__ Wpk,
                                               const float* __restrict__ bias,
                                               const unsigned short* __restrict__ resid16,
                                               const float* __restrict__ gamma,
                                               const float* __restrict__ beta,
                                               unsigned short* __restrict__ out16) {
    __shared__ unsigned short Ws[16384];
    __shared__ unsigned short Hs[64][136];
    int tid = threadIdx.x;
    long base = (long)blockIdx.x * 64;
    {
        const uint4* s4 = (const uint4*)Wpk;
        uint4* d4 = (uint4*)Ws;
        for (int i = tid; i < 2048; i += 256) d4[i] = s4[i];
        const unsigned short* hsrc = in16 + base * 128;
        for (int i = tid; i < 1024; i += 256) {
            int r = i >> 4, c8 = i & 15;
            *(uint4*)&Hs[r][c8 * 8] = *(const uint4*)&hsrc[r * 128 + c8 * 8];
        }
    }
    __syncthreads();
    int wv = tid >> 6, lane = tid & 63;
    int ql = lane & 15, qg = lane >> 4;
    f32x4 acc[8];
#pragma unroll
    for (int jt = 0; jt < 8; jt++) acc[jt] = (f32x4){0.f, 0.f, 0.f, 0.f};
#pragma unroll
    for (int kt = 0; kt < 8; kt++) {
        bf16x4 af = *(const bf16x4*)&Hs[wv * 16 + ql][kt * 16 + qg * 4];
#pragma unroll
        for (int jt = 0; jt < 8; jt++) {
            bf16x4 bf = *(const bf16x4*)&Ws[((jt * 8 + kt) * 64 + lane) * 4];
            acc[jt] = __builtin_amdgcn_mfma_f32_16x16x16bf16_1k(af, bf, acc[jt], 0, 0, 0);
        }
    }
    if (MODE >= 1) {
#pragma unroll
        for (int jt = 0; jt < 8; jt++) {
            float bv = bias[jt * 16 + ql];
#pragma unroll
            for (int r = 0; r < 4; r++) acc[jt][r] += bv;
        }
    }
    if (MODE == 2) {
#pragma unroll
        for (int jt = 0; jt < 8; jt++)
#pragma unroll
            for (int r = 0; r < 4; r++)
                acc[jt][r] += bf2f(resid16[(base + wv * 16 + qg * 4 + r) * 128 + jt * 16 + ql]);
        float s[4], s2[4], mean[4], istd[4];
#pragma unroll
        for (int r = 0; r < 4; r++) { s[r] = 0.f; s2[r] = 0.f; }
#pragma unroll
        for (int jt = 0; jt < 8; jt++)
#pragma unroll
            for (int r = 0; r < 4; r++) { float v = acc[jt][r]; s[r] += v; s2[r] += v * v; }
#pragma unroll
        for (int off = 1; off < 16; off <<= 1)
#pragma unroll
            for (int r = 0; r < 4; r++) {
                s[r] += __shfl_xor(s[r], off);
                s2[r] += __shfl_xor(s2[r], off);
            }
#pragma unroll
        for (int r = 0; r < 4; r++) {
            mean[r] = s[r] * (1.f / 128.f);
            float var = s2[r] * (1.f / 128.f) - mean[r] * mean[r];
            istd[r] = rsqrtf(var + EPS);
        }
#pragma unroll
        for (int jt = 0; jt < 8; jt++) {
            float gv = gamma[jt * 16 + ql], bev = beta[jt * 16 + ql];
#pragma unroll
            for (int r = 0; r < 4; r++)
                acc[jt][r] = (acc[jt][r] - mean[r]) * istd[r] * gv + bev;
        }
    }
#pragma unroll
    for (int jt = 0; jt < 8; jt++)
#pragma unroll
        for (int r = 0; r < 4; r++)
            Hs[wv * 16 + qg * 4 + r][jt * 16 + ql] = bfbits(acc[jt][r]);
#pragma unroll
    for (int p = 0; p < 4; p++) {
        int rl = p * 4 + qg;
        uint4 v = *(const uint4*)&Hs[wv * 16 + rl][ql * 8];
        *(uint4*)&out16[(base + wv * 16 + rl) * 128 + ql * 8] = v;
    }
}

template <int MODE>
__global__ __launch_bounds__(256) void gemm_mfma(const unsigned short* __restrict__ in16,
                                                 const unsigned short* __restrict__ Wpk,
                                                 const float* __restrict__ bias,
                                                 const unsigned short* __restrict__ resid16,
                                                 const float* __restrict__ gamma,
                                                 const float* __restrict__ beta,
                                                 unsigned short* __restrict__ out16) {
    gemm_mfma_body<MODE>(in16, Wpk, bias, resid16, gamma, beta, out16);
}

__global__ __launch_bounds__(256) void gemm_qkv(const unsigned short* __restrict__ in16,
                                                const unsigned short* __restrict__ Wpk,
                                                const float* __restrict__ bT,
                                                unsigned short* __restrict__ outb) {
    int y = blockIdx.y;
    gemm_mfma_body<1>(in16, Wpk + (3 + y) * 16384, bT + y * 128, nullptr, nullptr, nullptr,
                      outb + (long)y * N_NODES * 128);
}

// ---------------- GCN aggregation v4: wave-per-node, 16-deep batched loads for MLP ----------
__global__ __launch_bounds__(256) void gcn_agg(const unsigned short* __restrict__ hW,
                                               const int* __restrict__ row_ptr,
                                               const int* __restrict__ srcs,
                                               const float* __restrict__ dis,
                                               const float* __restrict__ bias,
                                               const float* __restrict__ gamma,
                                               const float* __restrict__ beta,
                                               unsigned short* __restrict__ h16, int with_resid) {
    int wv = threadIdx.x >> 6, lane = threadIdx.x & 63;
    int n = blockIdx.x * 4 + wv;
    int r0 = row_ptr[n], r1 = row_ptr[n + 1];
    float dn = dis[n];
    unsigned su = *(const unsigned*)&hW[(long)n * 128 + lane * 2];
    float dnn = dn * dn;
    float a0 = bf2f((unsigned short)(su & 0xffff)) * dnn;
    float a1 = bf2f((unsigned short)(su >> 16)) * dnn;
    for (int b = r0; b < r1; b += 64) {
        int cnt = min(64, r1 - b);
        int sv = n;          // pad: valid (hot) address, zero coefficient
        float cv = 0.f;
        if (lane < cnt) {
            sv = srcs[b + lane];
            cv = dis[sv] * dn;
        }
        int cntR = (cnt + 15) & ~15;
        for (int j = 0; j < cntR; j += 16) {
            unsigned u[16];
#pragma unroll
            for (int t = 0; t < 16; t++) {
                int s = __builtin_amdgcn_readlane(sv, j + t);
                u[t] = *(const unsigned*)&hW[(long)s * 128 + lane * 2];
            }
#pragma unroll
            for (int t = 0; t < 16; t++) {
                float c = __builtin_bit_cast(float,
                            __builtin_amdgcn_readlane(__builtin_bit_cast(int, cv), j + t));
                a0 += bf2f((unsigned short)(u[t] & 0xffff)) * c;
                a1 += bf2f((unsigned short)(u[t] >> 16)) * c;
            }
        }
    }
    float2 bb = *(const float2*)&bias[lane * 2];
    a0 += bb.x;
    a1 += bb.y;
    float s = a0 + a1, s2 = a0 * a0 + a1 * a1;
#pragma unroll
    for (int off = 1; off < 64; off <<= 1) { s += __shfl_xor(s, off); s2 += __shfl_xor(s2, off); }
    float mean = s * (1.f / 128.f);
    float var = s2 * (1.f / 128.f) - mean * mean;
    float is = rsqrtf(var + EPS);
    float2 gg = *(const float2*)&gamma[lane * 2];
    float2 be2 = *(const float2*)&beta[lane * 2];
    float y0 = fmaxf((a0 - mean) * is * gg.x + be2.x, 0.f);
    float y1 = fmaxf((a1 - mean) * is * gg.y + be2.y, 0.f);
    if (with_resid) {
        unsigned ru = *(const unsigned*)&h16[(long)n * 128 + lane * 2];
        y0 += bf2f((unsigned short)(ru & 0xffff));
        y1 += bf2f((unsigned short)(ru >> 16));
    }
    unsigned outu = (unsigned)bfbits(y0) | ((unsigned)bfbits(y1) << 16);
    *(unsigned*)&h16[(long)n * 128 + lane * 2] = outu;
}

// ---------------- attention: MFMA (swapped QK^T), bf16 output ----------------
__global__ __launch_bounds__(256) void attention(const unsigned short* __restrict__ q16,
                                                 const unsigned short* __restrict__ k16,
                                                 const unsigned short* __restrict__ v16,
                                                 unsigned short* __restrict__ o16) {
    int g = blockIdx.x, hh = blockIdx.y;
    int tid = threadIdx.x;
    long gbase = ((long)g * NPG) * 128 + hh * 16;
    __shared__ unsigned short Ksh[256][24];
    __shared__ unsigned short Qsh[256][24];
    __shared__ unsigned short Vt[16][264];
    {
        const unsigned short* kp = k16 + gbase + (long)tid * 128;
        uint4 a = *(const uint4*)kp, b = *(const uint4*)(kp + 8);
        *(uint4*)&Ksh[tid][0] = a; *(uint4*)&Ksh[tid][8] = b;
        const unsigned short* qp = q16 + gbase + (long)tid * 128;
        uint4 c = *(const uint4*)qp, d = *(const uint4*)(qp + 8);
        *(uint4*)&Qsh[tid][0] = c; *(uint4*)&Qsh[tid][8] = d;
        const unsigned short* vp = v16 + gbase + (long)tid * 128;
#pragma unroll
        for (int dd = 0; dd < 16; dd++) Vt[dd][tid] = vp[dd];
    }
    __syncthreads();
    int wv = tid >> 6, lane = tid & 63;
    int qg = lane >> 4, ql = lane & 15;
    bf16x4 vfrag[16];
#pragma unroll
    for (int kt = 0; kt < 16; kt++)
        vfrag[kt] = *(const bf16x4*)&Vt[ql][kt * 16 + qg * 4];
    const float C = 0.36067376022224085f;   // 0.25 * log2(e)
    for (int qi = 0; qi < 4; qi++) {
        int qt = wv * 4 + qi;
        bf16x4 qfrag = *(const bf16x4*)&Qsh[qt * 16 + ql][qg * 4];
        float lsum = 0.f;
        bf16x4 pb[16];
        f32x4 z4 = {0.f, 0.f, 0.f, 0.f};
#pragma unroll
        for (int kt = 0; kt < 16; kt++) {
            bf16x4 kfrag = *(const bf16x4*)&Ksh[kt * 16 + ql][qg * 4];
            f32x4 s4 = __builtin_amdgcn_mfma_f32_16x16x16bf16_1k(kfrag, qfrag, z4, 0, 0, 0);
            bf16x4 pbk;
#pragma unroll
            for (int r = 0; r < 4; r++) {
                float pv = exp2f(s4[r] * C);
                lsum += pv;
                pbk[r] = (short)bfbits(pv);
            }
            pb[kt] = pbk;
        }
        f32x4 oacc = {0.f, 0.f, 0.f, 0.f};
#pragma unroll
        for (int kt = 0; kt < 16; kt++)
            oacc = __builtin_amdgcn_mfma_f32_16x16x16bf16_1k(vfrag[kt], pb[kt], oacc, 0, 0, 0);
        lsum += __shfl_xor(lsum, 16);
        lsum += __shfl_xor(lsum, 32);
        float inv = 1.f / lsum;
        unsigned short* op = o16 + gbase + (long)(qt * 16 + ql) * 128 + 4 * qg;
        ushort4 st;
        st.x = bfbits(oacc[0] * inv);
        st.y = bfbits(oacc[1] * inv);
        st.z = bfbits(oacc[2] * inv);
        st.w = bfbits(oacc[3] * inv);
        *(ushort4*)op = st;
    }
}

// ---------------- pooling ----------------
__global__ __launch_bounds__(256) void pool_kernel(const unsigned short* __restrict__ hg,
                                                   float* __restrict__ pooled) {
    int g = blockIdx.x;
    int lane = threadIdx.x & 63, grp = threadIdx.x >> 6;
    __shared__ float ssum[4][128];
    __shared__ float smax[4][128];
    float s0 = 0.f, s1 = 0.f, m0 = -1e30f, m1 = -1e30f;
    for (int i = grp * 64; i < grp * 64 + 64; i++) {
        unsigned u = *(const unsigned*)&hg[((long)g * NPG + i) * 128 + lane * 2];
        float v0 = bf2f((unsigned short)(u & 0xffff));
        float v1 = bf2f((unsigned short)(u >> 16));
        s0 += v0; s1 += v1;
        m0 = fmaxf(m0, v0); m1 = fmaxf(m1, v1);
    }
    ssum[grp][lane * 2] = s0; ssum[grp][lane * 2 + 1] = s1;
    smax[grp][lane * 2] = m0; smax[grp][lane * 2 + 1] = m1;
    __syncthreads();
    if (grp == 0) {
        for (int jj = lane; jj < 128; jj += 64) {
            float ts = ssum[0][jj] + ssum[1][jj] + ssum[2][jj] + ssum[3][jj];
            float tm = fmaxf(fmaxf(smax[0][jj], smax[1][jj]), fmaxf(smax[2][jj], smax[3][jj]));
            pooled[g * 384 + jj] = ts * (1.f / 256.f);
            pooled[g * 384 + 128 + jj] = tm;
            pooled[g * 384 + 256 + jj] = ts;
        }
    }
}

// ---------------- classifier ----------------
__global__ __launch_bounds__(128) void classifier(const float* __restrict__ pooled,
                                                  const float* __restrict__ W1, const float* __restrict__ b1,
                                                  const float* __restrict__ g1, const float* __restrict__ be1,
                                                  const float* __restrict__ W2, const float* __restrict__ b2,
                                                  const float* __restrict__ W3, const float* __restrict__ b3,
                                                  float* __restrict__ out) {
    int g = blockIdx.x, j = threadIdx.x;
    __shared__ float pl[384];
    __shared__ float z1s[128];
    __shared__ float z2s[64];
    __shared__ float red[4];
    for (int i = j; i < 384; i += 128) pl[i] = pooled[g * 384 + i];
    __syncthreads();
    float acc = b1[j];
    for (int kk = 0; kk < 384; kk++) acc += pl[kk] * W1[kk * 128 + j];
    float m, is;
    ln_stats128(acc, m, is, red);
    float y = fmaxf((acc - m) * is * g1[j] + be1[j], 0.f);
    z1s[j] = y;
    __syncthreads();
    if (j < 64) {
        float a2 = b2[j];
        for (int kk = 0; kk < 128; kk++) a2 += z1s[kk] * W2[kk * 64 + j];
        z2s[j] = fmaxf(a2, 0.f);
    }
    __syncthreads();
    if (j < 64) {
        float vv = z2s[j];
        float p0 = vv * W3[j * 2];
        float p1 = vv * W3[j * 2 + 1];
#pragma unroll
        for (int off = 32; off; off >>= 1) { p0 += __shfl_xor(p0, off); p1 += __shfl_xor(p1, off); }
        if (j == 0) {
            out[g * 2] = p0 + b3[0];
            out[g * 2 + 1] = p1 + b3[1];
        }
    }
}

// ---------------- launch ----------------
extern "C" void kernel_launch(void* const* d_in, const int* in_sizes, int n_in,
                              void* d_out, int out_size, void* d_ws, size_t ws_size,
                              hipStream_t stream) {
    const float* x = (const float*)d_in[0];
    const int* ei = (const int*)d_in[1];
    const float* W_in = (const float*)d_in[3];
    const float* b_in = (const float*)d_in[4];
    const float* g_in = (const float*)d_in[5];
    const float* be_in = (const float*)d_in[6];
    const float* Wc = (const float*)d_in[7];
    const float* bc = (const float*)d_in[8];
    const float* gn = (const float*)d_in[9];
    const float* bn = (const float*)d_in[10];
    const float* Wq = (const float*)d_in[11];
    const float* bq = (const float*)d_in[12];
    const float* Wk = (const float*)d_in[13];
    const float* bk = (const float*)d_in[14];
    const float* Wv = (const float*)d_in[15];
    const float* bv = (const float*)d_in[16];
    const float* Wo = (const float*)d_in[17];
    const float* bo = (const float*)d_in[18];
    const float* ga = (const float*)d_in[19];
    const float* ba = (const float*)d_in[20];
    const float* W1 = (const float*)d_in[21];
    const float* b1 = (const float*)d_in[22];
    const float* g1 = (const float*)d_in[23];
    const float* be1 = (const float*)d_in[24];
    const float* W2 = (const float*)d_in[25];
    const float* b2 = (const float*)d_in[26];
    const float* W3 = (const float*)d_in[27];
    const float* b3 = (const float*)d_in[28];
    float* out = (float*)d_out;

    const long NF = (long)N_NODES * 128;
    unsigned char* wsb = (unsigned char*)d_ws;
    const size_t MB = 1 << 20;
    unsigned short* h16 = (unsigned short*)(wsb);             // 8MB
    unsigned short* hw16 = (unsigned short*)(wsb + 8 * MB);   // 8MB
    unsigned short* qkv16 = (unsigned short*)(wsb + 16 * MB); // 24MB
    unsigned short* o16 = (unsigned short*)(wsb + 40 * MB);   // 8MB
    unsigned short* hg16 = (unsigned short*)(wsb + 48 * MB);  // 8MB
    unsigned short* Wpk = (unsigned short*)(wsb + 56 * MB);   // 224KB
    int* packed = (int*)(wsb + 57 * MB);                      // 4MB
    int* srcs = (int*)(wsb + 61 * MB);                        // 4MB
    int* row_ptr = (int*)(wsb + 65 * MB);                     // 128KB+4
    float* dis = (float*)(wsb + 66 * MB);                     // 128KB
    float* bT = (float*)(wsb + 67 * MB);                      // 1.5KB
    float* pooled = (float*)(wsb + 67 * MB + 4096);           // 192KB
    int* bucket_cnt = (int*)(wsb + 68 * MB);                  // 256
    int* bucket_base = bucket_cnt + 256;                      // 257
    int* bucket_fill = bucket_base + 257;                     // 256

    const int* e_src = ei;
    const int* e_dst = ei + E_EDGES;

    hipMemsetAsync(bucket_cnt, 0, 256 * sizeof(int), stream);
    prep_weights<<<dim3(64, 7), 256, 0, stream>>>(Wc, Wq, Wk, Wv, Wo, bq, bk, bv, Wpk, bT);
    bucket_count<<<E_EDGES / CHUNK, 256, 0, stream>>>(e_dst, bucket_cnt);
    scan_buckets<<<1, 256, 0, stream>>>(bucket_cnt, bucket_base, bucket_fill);
    bucket_scatter<<<E_EDGES / CHUNK, 256, 0, stream>>>(e_src, e_dst, bucket_fill, packed);
    csr_build<<<256, 256, 0, stream>>>(bucket_base, packed, srcs, row_ptr, dis);

    input_proj<<<N_NODES, 128, 0, stream>>>(x, W_in, b_in, g_in, be_in, h16);

    for (int i = 0; i < 3; i++) {
        gemm_mfma<0><<<N_NODES / 64, 256, 0, stream>>>(h16, Wpk + i * 16384, nullptr, nullptr,
                                                       nullptr, nullptr, hw16);
        gcn_agg<<<N_NODES / 4, 256, 0, stream>>>(hw16, row_ptr, srcs, dis, bc + i * 128,
                                                 gn + i * 128, bn + i * 128, h16, i > 0);
    }

    gemm_qkv<<<dim3(N_NODES / 64, 3), 256, 0, stream>>>(h16, Wpk, bT, qkv16);

    attention<<<dim3(G_GRAPHS, NH), 256, 0, stream>>>(qkv16, qkv16 + NF, qkv16 + 2 * NF, o16);

    gemm_mfma<2><<<N_NODES / 64, 256, 0, stream>>>(o16, Wpk + 6 * 16384, bo, h16, ga, ba, hg16);

    pool_kernel<<<G_GRAPHS, 256, 0, stream>>>(hg16, pooled);
    classifier<<<G_GRAPHS, 128, 0, stream>>>(pooled, W1, b1, g1, be1, W2, b2, W3, b3, out);
}